// Round 1
// baseline (965.402 us; speedup 1.0000x reference)
//
#include <hip/hip_runtime.h>
#include <math.h>

#define N_NODES 50000
#define N_EDGES 800000
#define DIN 128
#define DH 128
#define EA_C 50
#define TC_C 50
#define DE 100      // EA_C + TC_C
#define FM 228      // DIN + DE
#define BN_EPS 1e-5f

// ---------------- CSR build ----------------
__global__ void k_count(const int* __restrict__ row, int* __restrict__ counts) {
  int e = blockIdx.x * 256 + threadIdx.x;
  if (e < N_EDGES) atomicAdd(&counts[row[e]], 1);
}

__global__ void k_scan(const int* __restrict__ counts, int* __restrict__ row_ptr,
                       int* __restrict__ cursor) {
  __shared__ int buf[256];
  __shared__ int carry;
  if (threadIdx.x == 0) carry = 0;
  __syncthreads();
  for (int base = 0; base < N_NODES; base += 256) {
    int i = base + threadIdx.x;
    int v = (i < N_NODES) ? counts[i] : 0;
    buf[threadIdx.x] = v;
    __syncthreads();
    for (int off = 1; off < 256; off <<= 1) {
      int t = (threadIdx.x >= off) ? buf[threadIdx.x - off] : 0;
      __syncthreads();
      buf[threadIdx.x] += t;
      __syncthreads();
    }
    int excl = buf[threadIdx.x] - v;
    if (i < N_NODES) { int p = carry + excl; row_ptr[i] = p; cursor[i] = p; }
    __syncthreads();
    if (threadIdx.x == 0) carry += buf[255];
    __syncthreads();
  }
  if (threadIdx.x == 0) row_ptr[N_NODES] = carry;
}

__global__ void k_fill(const int* __restrict__ row, const int* __restrict__ col,
                       int* __restrict__ cursor, int* __restrict__ col_s,
                       int* __restrict__ eid_s) {
  int e = blockIdx.x * 256 + threadIdx.x;
  if (e < N_EDGES) {
    int r = row[e];
    int slot = atomicAdd(&cursor[r], 1);
    col_s[slot] = col[e];
    eid_s[slot] = e;
  }
}

// ---------------- per-edge time log ----------------
__global__ void k_tlog(const int* __restrict__ tim, float* __restrict__ tlog) {
  int e = blockIdx.x * 256 + threadIdx.x;
  if (e < N_EDGES) tlog[e] = __logf((float)tim[e] + 1.0f);
}

// ---------------- edge-embedding aggregation (once, reused by all layers) ----
// block = 128 threads = 2 waves. wave0: ea channels (lane<50), wave1: cos channels.
__global__ void k_aggE(const int* __restrict__ row_ptr, const int* __restrict__ eid_s,
                       const int* __restrict__ attr, const int* __restrict__ dire,
                       const float* __restrict__ tlog,
                       const float* __restrict__ emb_type, const float* __restrict__ emb_dir,
                       const float* __restrict__ w_t, const float* __restrict__ b_t,
                       float* __restrict__ aggE) {
  int n = blockIdx.x;
  int wave = threadIdx.x >> 6;
  int lane = threadIdx.x & 63;
  if (lane >= EA_C) return;
  int s = row_ptr[n], epos = row_ptr[n + 1];
  float acc = 0.f;
  if (wave == 0) {
    for (int p = s; p < epos; ++p) {
      int e = eid_s[p];
      acc += emb_type[attr[e] * EA_C + lane] + emb_dir[dire[e] * EA_C + lane];
    }
    aggE[(size_t)n * DE + lane] = acc;
  } else {
    float w = w_t[lane], b = b_t[lane];
    for (int p = s; p < epos; ++p) {
      int e = eid_s[p];
      acc += __cosf(tlog[e] * w + b);
    }
    aggE[(size_t)n * DE + EA_C + lane] = acc;
  }
}

// ---------------- neighbor aggregation of 128-dim h ----------------
// block 256 = 4 waves, one node per wave, lane covers 2 channels via float2.
__global__ void k_aggH(const float* __restrict__ h, const int* __restrict__ row_ptr,
                       const int* __restrict__ col_s, float* __restrict__ aggH) {
  int wave = threadIdx.x >> 6, lane = threadIdx.x & 63;
  int n = blockIdx.x * 4 + wave;
  if (n >= N_NODES) return;
  int s = row_ptr[n], epos = row_ptr[n + 1];
  float ax = 0.f, ay = 0.f;
  for (int p = s; p < epos; ++p) {
    int c = col_s[p];
    float2 v = *reinterpret_cast<const float2*>(h + (size_t)c * DH + 2 * lane);
    ax += v.x; ay += v.y;
  }
  float2 o; o.x = ax; o.y = ay;
  *reinterpret_cast<float2*>(aggH + (size_t)n * DH + 2 * lane) = o;
}

// ---------------- weight transpose (+scale fold) ----------------
__global__ void k_transpose(const float* __restrict__ W, float* __restrict__ WT,
                            int dout, int kin, int fan, int koff, float scale) {
  int idx = blockIdx.x * 256 + threadIdx.x;
  if (idx >= dout * kin) return;
  int k = idx / dout, o = idx - k * dout;
  WT[k * dout + o] = W[o * fan + koff + k] * scale;
}

__global__ void k_bias(const float* __restrict__ bm, const float* __restrict__ br,
                       float* __restrict__ bv) {
  int o = threadIdx.x;
  if (o < DH) bv[o] = 0.5f * bm[o] + br[o];
}

// ---------------- dense GEMM: out[N,128] = A1@W1T + A2@W2T + A3@W3T + bv ----
#define BM 64
#define BK 32
__global__ __launch_bounds__(256) void k_gemm(
    const float* __restrict__ A1, const float* __restrict__ W1T,   // aggH K=128
    const float* __restrict__ A2, const float* __restrict__ W2T,   // aggE K=100
    const float* __restrict__ A3, const float* __restrict__ W3T,   // h    K=128
    const float* __restrict__ bv, float* __restrict__ out) {
  __shared__ float As[BM][BK];
  __shared__ float Ws[BK][DH];
  int tid = threadIdx.x;
  int to = tid & 31, tn = tid >> 5;
  int node0 = blockIdx.x * BM;
  float acc[8][4];
#pragma unroll
  for (int i = 0; i < 8; ++i)
#pragma unroll
    for (int j = 0; j < 4; ++j) acc[i][j] = 0.f;

  const float* Aps[3] = {A1, A2, A3};
  const float* Wps[3] = {W1T, W2T, W3T};
  const int Ks[3] = {128, 100, 128};
  const int ldas[3] = {128, 100, 128};

  for (int part = 0; part < 3; ++part) {
    const float* A = Aps[part];
    const float* WT = Wps[part];
    int K = Ks[part], lda = ldas[part];
    for (int kc = 0; kc < K; kc += BK) {
      for (int idx = tid; idx < BM * BK; idx += 256) {
        int r = idx >> 5, c = idx & 31;
        int n = node0 + r, k = kc + c;
        As[r][c] = (n < N_NODES && k < K) ? A[(size_t)n * lda + k] : 0.f;
      }
      for (int idx = tid; idx < BK * DH; idx += 256) {
        int kk = idx >> 7, o = idx & 127;
        int k = kc + kk;
        Ws[kk][o] = (k < K) ? WT[(size_t)k * DH + o] : 0.f;
      }
      __syncthreads();
#pragma unroll
      for (int kk = 0; kk < BK; ++kk) {
        float4 w = *reinterpret_cast<const float4*>(&Ws[kk][to * 4]);
#pragma unroll
        for (int i = 0; i < 8; ++i) {
          float a = As[tn * 8 + i][kk];
          acc[i][0] += a * w.x; acc[i][1] += a * w.y;
          acc[i][2] += a * w.z; acc[i][3] += a * w.w;
        }
      }
      __syncthreads();
    }
  }
  float4 b4 = *reinterpret_cast<const float4*>(&bv[to * 4]);
#pragma unroll
  for (int i = 0; i < 8; ++i) {
    int n = node0 + tn * 8 + i;
    if (n < N_NODES) {
      float4 v;
      v.x = acc[i][0] + b4.x; v.y = acc[i][1] + b4.y;
      v.z = acc[i][2] + b4.z; v.w = acc[i][3] + b4.w;
      *reinterpret_cast<float4*>(&out[(size_t)n * DH + to * 4]) = v;
    }
  }
}

// ---------------- BatchNorm stats (sum, sumsq per channel) ----------------
__global__ void k_bnstats(const float* __restrict__ x, float* __restrict__ stats) {
  int c = threadIdx.x & 127;
  int half = threadIdx.x >> 7;
  float s = 0.f, q = 0.f;
  for (int r = blockIdx.x * 2 + half; r < N_NODES; r += gridDim.x * 2) {
    float v = x[(size_t)r * DH + c];
    s += v; q += v * v;
  }
  __shared__ float ls[256], lq[256];
  ls[threadIdx.x] = s; lq[threadIdx.x] = q;
  __syncthreads();
  if (half == 0) {
    s += ls[128 + c]; q += lq[128 + c];
    atomicAdd(&stats[c], s);
    atomicAdd(&stats[128 + c], q);
  }
}

__global__ void k_bnapply(float* __restrict__ x, const float* __restrict__ stats,
                          const float* __restrict__ g, const float* __restrict__ be,
                          int elu) {
  int idx = blockIdx.x * 256 + threadIdx.x;
  if (idx >= N_NODES * DH) return;
  int c = idx & 127;
  float mu = stats[c] * (1.0f / N_NODES);
  float var = stats[128 + c] * (1.0f / N_NODES) - mu * mu;
  float v = x[idx];
  float y = (v - mu) * rsqrtf(var + BN_EPS) * g[c] + be[c];
  if (elu) y = y > 0.f ? y : expm1f(y);
  x[idx] = y;
}

// ---------------- layer 2 dense (project-first, dout=2) ----------------
__global__ void k_l2_dense(const float* __restrict__ h, const float* __restrict__ aggE,
                           const float* __restrict__ Wm2, const float* __restrict__ bm2,
                           const float* __restrict__ Wr2, const float* __restrict__ br2,
                           float* __restrict__ val, float* __restrict__ pm) {
  int wave = threadIdx.x >> 6, lane = threadIdx.x & 63;
  int n = blockIdx.x * 4 + wave;
  if (n >= N_NODES) return;
  const float* hr = h + (size_t)n * DH;
  const float* er = aggE + (size_t)n * DE;
  float h0 = hr[lane], h1 = hr[lane + 64];
  float e0 = er[lane];
  float e1 = (lane < DE - 64) ? er[lane + 64] : 0.f;

  float pm0 = h0 * Wm2[lane] + h1 * Wm2[lane + 64];
  float pm1 = h0 * Wm2[FM + lane] + h1 * Wm2[FM + lane + 64];
  float ve0 = e0 * Wm2[DIN + lane] + ((lane < DE - 64) ? e1 * Wm2[DIN + lane + 64] : 0.f);
  float ve1 = e0 * Wm2[FM + DIN + lane] + ((lane < DE - 64) ? e1 * Wm2[FM + DIN + lane + 64] : 0.f);
  float pr0 = h0 * Wr2[lane] + h1 * Wr2[lane + 64];
  float pr1 = h0 * Wr2[DH + lane] + h1 * Wr2[DH + lane + 64];

#pragma unroll
  for (int m = 32; m >= 1; m >>= 1) {
    pm0 += __shfl_xor(pm0, m, 64); pm1 += __shfl_xor(pm1, m, 64);
    ve0 += __shfl_xor(ve0, m, 64); ve1 += __shfl_xor(ve1, m, 64);
    pr0 += __shfl_xor(pr0, m, 64); pr1 += __shfl_xor(pr1, m, 64);
  }
  if (lane == 0) {
    val[n * 2 + 0] = 0.5f * (ve0 + bm2[0]) + pr0 + br2[0];
    val[n * 2 + 1] = 0.5f * (ve1 + bm2[1]) + pr1 + br2[1];
    pm[n * 2 + 0] = pm0;
    pm[n * 2 + 1] = pm1;
  }
}

__global__ void k_agg2(const int* __restrict__ row_ptr, const int* __restrict__ col_s,
                       const float* __restrict__ pm, float* __restrict__ val) {
  int n = blockIdx.x * 256 + threadIdx.x;
  if (n >= N_NODES) return;
  float a0 = 0.f, a1 = 0.f;
  int s = row_ptr[n], e = row_ptr[n + 1];
  for (int p = s; p < e; ++p) {
    int c = col_s[p];
    a0 += pm[c * 2]; a1 += pm[c * 2 + 1];
  }
  val[n * 2] += 0.5f * a0;
  val[n * 2 + 1] += 0.5f * a1;
}

__global__ void k_bnstats2(const float* __restrict__ val, float* __restrict__ s4) {
  float s0 = 0.f, q0 = 0.f, s1 = 0.f, q1 = 0.f;
  for (int n = blockIdx.x * 256 + threadIdx.x; n < N_NODES; n += gridDim.x * 256) {
    float v0 = val[n * 2], v1 = val[n * 2 + 1];
    s0 += v0; q0 += v0 * v0; s1 += v1; q1 += v1 * v1;
  }
  __shared__ float b[256][4];
  b[threadIdx.x][0] = s0; b[threadIdx.x][1] = q0;
  b[threadIdx.x][2] = s1; b[threadIdx.x][3] = q1;
  __syncthreads();
  for (int off = 128; off >= 1; off >>= 1) {
    if (threadIdx.x < off)
      for (int j = 0; j < 4; ++j) b[threadIdx.x][j] += b[threadIdx.x + off][j];
    __syncthreads();
  }
  if (threadIdx.x == 0)
    for (int j = 0; j < 4; ++j) atomicAdd(&s4[j], b[0][j]);
}

__global__ void k_final(const float* __restrict__ val, const float* __restrict__ s4,
                        const float* __restrict__ g2, const float* __restrict__ be2,
                        float* __restrict__ out) {
  int n = blockIdx.x * 256 + threadIdx.x;
  if (n >= N_NODES) return;
  float mu0 = s4[0] * (1.f / N_NODES), var0 = s4[1] * (1.f / N_NODES) - mu0 * mu0;
  float mu1 = s4[2] * (1.f / N_NODES), var1 = s4[3] * (1.f / N_NODES) - mu1 * mu1;
  float y0 = (val[n * 2] - mu0) * rsqrtf(var0 + BN_EPS) * g2[0] + be2[0];
  float y1 = (val[n * 2 + 1] - mu1) * rsqrtf(var1 + BN_EPS) * g2[1] + be2[1];
  float m = fmaxf(y0, y1);
  float lse = m + __logf(__expf(y0 - m) + __expf(y1 - m));
  out[n * 2] = y0 - lse;
  out[n * 2 + 1] = y1 - lse;
}

// ---------------- launch ----------------
extern "C" void kernel_launch(void* const* d_in, const int* in_sizes, int n_in,
                              void* d_out, int out_size, void* d_ws, size_t ws_size,
                              hipStream_t stream) {
  (void)in_sizes; (void)n_in; (void)out_size; (void)ws_size;
  const float* x        = (const float*)d_in[0];
  const int*   eidx     = (const int*)d_in[1];
  const int*   row      = eidx;
  const int*   col      = eidx + N_EDGES;
  const int*   attr     = (const int*)d_in[2];
  const int*   tim      = (const int*)d_in[3];
  const int*   dire     = (const int*)d_in[4];
  const float* emb_type = (const float*)d_in[5];
  const float* emb_dir  = (const float*)d_in[6];
  const float* w_t      = (const float*)d_in[7];
  const float* b_t      = (const float*)d_in[8];
  const float* Wm[3] = {(const float*)d_in[9],  (const float*)d_in[15], (const float*)d_in[21]};
  const float* bm[3] = {(const float*)d_in[10], (const float*)d_in[16], (const float*)d_in[22]};
  const float* Wr[3] = {(const float*)d_in[11], (const float*)d_in[17], (const float*)d_in[23]};
  const float* br[3] = {(const float*)d_in[12], (const float*)d_in[18], (const float*)d_in[24]};
  const float* g[3]  = {(const float*)d_in[13], (const float*)d_in[19], (const float*)d_in[25]};
  const float* be[3] = {(const float*)d_in[14], (const float*)d_in[20], (const float*)d_in[26]};
  float* out = (float*)d_out;

  // workspace layout
  char* p = (char*)d_ws;
  float* aggE = (float*)p;  p += sizeof(float) * (size_t)N_NODES * DE;
  float* aggH = (float*)p;  p += sizeof(float) * (size_t)N_NODES * DH;
  float* hA   = (float*)p;  p += sizeof(float) * (size_t)N_NODES * DH;
  float* val  = (float*)p;  p += sizeof(float) * (size_t)N_NODES * 2;
  float* pmb  = (float*)p;  p += sizeof(float) * (size_t)N_NODES * 2;
  float* WmHT[2]; float* WmET[2]; float* WrT[2]; float* bv[2];
  for (int l = 0; l < 2; ++l) {
    WmHT[l] = (float*)p; p += sizeof(float) * DIN * DH;   // 128x128
    WmET[l] = (float*)p; p += sizeof(float) * DE * DH;    // 100x128
    WrT[l]  = (float*)p; p += sizeof(float) * DIN * DH;   // 128x128
    bv[l]   = (float*)p; p += sizeof(float) * DH;
  }
  float* stats = (float*)p; p += sizeof(float) * 520;     // L0:0..255, L1:256..511, L2:512..515
  float* tlog  = (float*)p; p += sizeof(float) * N_EDGES;
  int* counts  = (int*)p;   p += sizeof(int) * N_NODES;
  int* cursor  = (int*)p;   p += sizeof(int) * N_NODES;
  int* row_ptr = (int*)p;   p += sizeof(int) * (N_NODES + 1);
  int* col_s   = (int*)p;   p += sizeof(int) * N_EDGES;
  int* eid_s   = (int*)p;   p += sizeof(int) * N_EDGES;

  const int EB = (N_EDGES + 255) / 256;      // 3125
  const int NB = (N_NODES + 255) / 256;      // 196

  hipMemsetAsync(counts, 0, sizeof(int) * N_NODES, stream);
  hipMemsetAsync(stats, 0, sizeof(float) * 520, stream);

  // CSR
  k_count<<<EB, 256, 0, stream>>>(row, counts);
  k_scan<<<1, 256, 0, stream>>>(counts, row_ptr, cursor);
  k_fill<<<EB, 256, 0, stream>>>(row, col, cursor, col_s, eid_s);
  k_tlog<<<EB, 256, 0, stream>>>(tim, tlog);

  // weight prep
  for (int l = 0; l < 2; ++l) {
    k_transpose<<<(DIN * DH + 255) / 256, 256, 0, stream>>>(Wm[l], WmHT[l], DH, DIN, FM, 0, 0.5f);
    k_transpose<<<(DE * DH + 255) / 256, 256, 0, stream>>>(Wm[l], WmET[l], DH, DE, FM, DIN, 0.5f);
    k_transpose<<<(DIN * DH + 255) / 256, 256, 0, stream>>>(Wr[l], WrT[l], DH, DIN, DIN, 0, 1.0f);
    k_bias<<<1, 128, 0, stream>>>(bm[l], br[l], bv[l]);
  }

  // edge-feature aggregation (shared by all layers)
  k_aggE<<<N_NODES, 128, 0, stream>>>(row_ptr, eid_s, attr, dire, tlog,
                                      emb_type, emb_dir, w_t, b_t, aggE);

  const int AB = (N_NODES + 3) / 4;          // 12500
  const int GB = (N_NODES + BM - 1) / BM;    // 782
  const int XB = (N_NODES * DH + 255) / 256; // 25000

  // layer 0: in x -> hA
  k_aggH<<<AB, 256, 0, stream>>>(x, row_ptr, col_s, aggH);
  k_gemm<<<GB, 256, 0, stream>>>(aggH, WmHT[0], aggE, WmET[0], x, WrT[0], bv[0], hA);
  k_bnstats<<<256, 256, 0, stream>>>(hA, stats);
  k_bnapply<<<XB, 256, 0, stream>>>(hA, stats, g[0], be[0], 1);

  // layer 1: hA -> hA (in-place safe: each GEMM block reads only its own rows)
  k_aggH<<<AB, 256, 0, stream>>>(hA, row_ptr, col_s, aggH);
  k_gemm<<<GB, 256, 0, stream>>>(aggH, WmHT[1], aggE, WmET[1], hA, WrT[1], bv[1], hA);
  k_bnstats<<<256, 256, 0, stream>>>(hA, stats + 256);
  k_bnapply<<<XB, 256, 0, stream>>>(hA, stats + 256, g[1], be[1], 1);

  // layer 2: project-first (dout=2), then aggregate 2-dim
  k_l2_dense<<<AB, 256, 0, stream>>>(hA, aggE, Wm[2], bm[2], Wr[2], br[2], val, pmb);
  k_agg2<<<NB, 256, 0, stream>>>(row_ptr, col_s, pmb, val);
  k_bnstats2<<<64, 256, 0, stream>>>(val, stats + 512);
  k_final<<<NB, 256, 0, stream>>>(val, stats + 512, g[2], be[2], out);
}

// Round 2
// 754.618 us; speedup vs baseline: 1.2793x; 1.2793x over previous
//
#include <hip/hip_runtime.h>
#include <math.h>

#define N_NODES 50000
#define N_EDGES 800000
#define DIN 128
#define DH 128
#define EA_C 50
#define TC_C 50
#define DE 100      // EA_C + TC_C
#define FM 228      // DIN + DE
#define BN_EPS 1e-5f
#define SCAN_NB ((N_NODES + 255) / 256)   // 196

// ---------------- CSR build ----------------
__global__ void k_count(const int* __restrict__ row, int* __restrict__ counts) {
  int e = blockIdx.x * 256 + threadIdx.x;
  if (e < N_EDGES) atomicAdd(&counts[row[e]], 1);
}

// stage A: per-block inclusive scan of 256 counts -> row_ptr (temp), block sums
__global__ void k_scan_a(const int* __restrict__ counts, int* __restrict__ incl,
                         int* __restrict__ bsum) {
  __shared__ int buf[256];
  int i = blockIdx.x * 256 + threadIdx.x;
  int v = (i < N_NODES) ? counts[i] : 0;
  buf[threadIdx.x] = v;
  __syncthreads();
#pragma unroll
  for (int off = 1; off < 256; off <<= 1) {
    int t = (threadIdx.x >= off) ? buf[threadIdx.x - off] : 0;
    __syncthreads();
    buf[threadIdx.x] += t;
    __syncthreads();
  }
  if (i < N_NODES) incl[i] = buf[threadIdx.x];
  if (threadIdx.x == 255) bsum[blockIdx.x] = buf[255];
}

// stage B: exclusive scan of block sums (196 values, one block)
__global__ void k_scan_b(const int* __restrict__ bsum, int* __restrict__ boff,
                         int* __restrict__ row_ptr) {
  __shared__ int buf[256];
  int v = (threadIdx.x < SCAN_NB) ? bsum[threadIdx.x] : 0;
  buf[threadIdx.x] = v;
  __syncthreads();
#pragma unroll
  for (int off = 1; off < 256; off <<= 1) {
    int t = (threadIdx.x >= off) ? buf[threadIdx.x - off] : 0;
    __syncthreads();
    buf[threadIdx.x] += t;
    __syncthreads();
  }
  if (threadIdx.x < SCAN_NB) boff[threadIdx.x] = buf[threadIdx.x] - v;
  if (threadIdx.x == 255) row_ptr[N_NODES] = buf[255];
}

// stage C: finalize exclusive scan, init cursor
__global__ void k_scan_c(const int* __restrict__ incl, const int* __restrict__ counts,
                         const int* __restrict__ boff, int* __restrict__ row_ptr,
                         int* __restrict__ cursor) {
  int i = blockIdx.x * 256 + threadIdx.x;
  if (i < N_NODES) {
    int p = incl[i] - counts[i] + boff[blockIdx.x];
    row_ptr[i] = p;
    cursor[i] = p;
  }
}

__global__ void k_fill(const int* __restrict__ row, const int* __restrict__ col,
                       int* __restrict__ cursor, int* __restrict__ col_s,
                       int* __restrict__ eid_s) {
  int e = blockIdx.x * 256 + threadIdx.x;
  if (e < N_EDGES) {
    int r = row[e];
    int slot = atomicAdd(&cursor[r], 1);
    col_s[slot] = col[e];
    eid_s[slot] = e;
  }
}

// ---------------- per-edge time log ----------------
__global__ void k_tlog(const int* __restrict__ tim, float* __restrict__ tlog) {
  int e = blockIdx.x * 256 + threadIdx.x;
  if (e < N_EDGES) tlog[e] = __logf((float)tim[e] + 1.0f);
}

// ---------------- edge-embedding aggregation (once, reused by all layers) ----
__global__ void k_aggE(const int* __restrict__ row_ptr, const int* __restrict__ eid_s,
                       const int* __restrict__ attr, const int* __restrict__ dire,
                       const float* __restrict__ tlog,
                       const float* __restrict__ emb_type, const float* __restrict__ emb_dir,
                       const float* __restrict__ w_t, const float* __restrict__ b_t,
                       float* __restrict__ aggE) {
  int n = blockIdx.x;
  int wave = threadIdx.x >> 6;
  int lane = threadIdx.x & 63;
  if (lane >= EA_C) return;
  int s = row_ptr[n], epos = row_ptr[n + 1];
  float acc = 0.f;
  if (wave == 0) {
    for (int p = s; p < epos; ++p) {
      int e = eid_s[p];
      acc += emb_type[attr[e] * EA_C + lane] + emb_dir[dire[e] * EA_C + lane];
    }
    aggE[(size_t)n * DE + lane] = acc;
  } else {
    float w = w_t[lane], b = b_t[lane];
    for (int p = s; p < epos; ++p) {
      int e = eid_s[p];
      acc += __cosf(tlog[e] * w + b);
    }
    aggE[(size_t)n * DE + EA_C + lane] = acc;
  }
}

// ---------------- neighbor aggregation of 128-dim h ----------------
__global__ void k_aggH(const float* __restrict__ h, const int* __restrict__ row_ptr,
                       const int* __restrict__ col_s, float* __restrict__ aggH) {
  int wave = threadIdx.x >> 6, lane = threadIdx.x & 63;
  int n = blockIdx.x * 4 + wave;
  if (n >= N_NODES) return;
  int s = row_ptr[n], epos = row_ptr[n + 1];
  float ax = 0.f, ay = 0.f;
  for (int p = s; p < epos; ++p) {
    int c = col_s[p];
    float2 v = *reinterpret_cast<const float2*>(h + (size_t)c * DH + 2 * lane);
    ax += v.x; ay += v.y;
  }
  float2 o; o.x = ax; o.y = ay;
  *reinterpret_cast<float2*>(aggH + (size_t)n * DH + 2 * lane) = o;
}

// ---------------- weight transpose (+scale fold) ----------------
__global__ void k_transpose(const float* __restrict__ W, float* __restrict__ WT,
                            int dout, int kin, int fan, int koff, float scale) {
  int idx = blockIdx.x * 256 + threadIdx.x;
  if (idx >= dout * kin) return;
  int k = idx / dout, o = idx - k * dout;
  WT[k * dout + o] = W[o * fan + koff + k] * scale;
}

__global__ void k_bias(const float* __restrict__ bm, const float* __restrict__ br,
                       float* __restrict__ bv) {
  int o = threadIdx.x;
  if (o < DH) bv[o] = 0.5f * bm[o] + br[o];
}

// ---------------- dense GEMM: out[N,128] = A1@W1T + A2@W2T + A3@W3T + bv ----
#define BM 64
#define BK 32
__global__ __launch_bounds__(256) void k_gemm(
    const float* __restrict__ A1, const float* __restrict__ W1T,   // aggH K=128
    const float* __restrict__ A2, const float* __restrict__ W2T,   // aggE K=100
    const float* __restrict__ A3, const float* __restrict__ W3T,   // h    K=128
    const float* __restrict__ bv, float* __restrict__ out) {
  __shared__ float As[BM][BK];
  __shared__ float Ws[BK][DH];
  int tid = threadIdx.x;
  int to = tid & 31, tn = tid >> 5;
  int node0 = blockIdx.x * BM;
  float acc[8][4];
#pragma unroll
  for (int i = 0; i < 8; ++i)
#pragma unroll
    for (int j = 0; j < 4; ++j) acc[i][j] = 0.f;

  const float* Aps[3] = {A1, A2, A3};
  const float* Wps[3] = {W1T, W2T, W3T};
  const int Ks[3] = {128, 100, 128};

  for (int part = 0; part < 3; ++part) {
    const float* A = Aps[part];
    const float* WT = Wps[part];
    int K = Ks[part];
    for (int kc = 0; kc < K; kc += BK) {
      for (int idx = tid; idx < BM * BK; idx += 256) {
        int r = idx >> 5, c = idx & 31;
        int n = node0 + r, k = kc + c;
        As[r][c] = (n < N_NODES && k < K) ? A[(size_t)n * K + k] : 0.f;
      }
      for (int idx = tid; idx < BK * DH; idx += 256) {
        int kk = idx >> 7, o = idx & 127;
        int k = kc + kk;
        Ws[kk][o] = (k < K) ? WT[(size_t)k * DH + o] : 0.f;
      }
      __syncthreads();
#pragma unroll
      for (int kk = 0; kk < BK; ++kk) {
        float4 w = *reinterpret_cast<const float4*>(&Ws[kk][to * 4]);
#pragma unroll
        for (int i = 0; i < 8; ++i) {
          float a = As[tn * 8 + i][kk];
          acc[i][0] += a * w.x; acc[i][1] += a * w.y;
          acc[i][2] += a * w.z; acc[i][3] += a * w.w;
        }
      }
      __syncthreads();
    }
  }
  float4 b4 = *reinterpret_cast<const float4*>(&bv[to * 4]);
#pragma unroll
  for (int i = 0; i < 8; ++i) {
    int n = node0 + tn * 8 + i;
    if (n < N_NODES) {
      float4 v;
      v.x = acc[i][0] + b4.x; v.y = acc[i][1] + b4.y;
      v.z = acc[i][2] + b4.z; v.w = acc[i][3] + b4.w;
      *reinterpret_cast<float4*>(&out[(size_t)n * DH + to * 4]) = v;
    }
  }
}

// ---------------- BatchNorm stats (sum, sumsq per channel) ----------------
__global__ void k_bnstats(const float* __restrict__ x, float* __restrict__ stats) {
  int c = threadIdx.x & 127;
  int half = threadIdx.x >> 7;
  float s = 0.f, q = 0.f;
  for (int r = blockIdx.x * 2 + half; r < N_NODES; r += gridDim.x * 2) {
    float v = x[(size_t)r * DH + c];
    s += v; q += v * v;
  }
  __shared__ float ls[256], lq[256];
  ls[threadIdx.x] = s; lq[threadIdx.x] = q;
  __syncthreads();
  if (half == 0) {
    s += ls[128 + c]; q += lq[128 + c];
    atomicAdd(&stats[c], s);
    atomicAdd(&stats[128 + c], q);
  }
}

__global__ void k_bnapply(float* __restrict__ x, const float* __restrict__ stats,
                          const float* __restrict__ g, const float* __restrict__ be,
                          int elu) {
  int idx = blockIdx.x * 256 + threadIdx.x;
  if (idx >= N_NODES * DH) return;
  int c = idx & 127;
  float mu = stats[c] * (1.0f / N_NODES);
  float var = stats[128 + c] * (1.0f / N_NODES) - mu * mu;
  float v = x[idx];
  float y = (v - mu) * rsqrtf(var + BN_EPS) * g[c] + be[c];
  if (elu) y = y > 0.f ? y : expm1f(y);
  x[idx] = y;
}

// ---------------- layer 2 dense (project-first, dout=2) ----------------
__global__ void k_l2_dense(const float* __restrict__ h, const float* __restrict__ aggE,
                           const float* __restrict__ Wm2, const float* __restrict__ bm2,
                           const float* __restrict__ Wr2, const float* __restrict__ br2,
                           float* __restrict__ val, float* __restrict__ pm) {
  int wave = threadIdx.x >> 6, lane = threadIdx.x & 63;
  int n = blockIdx.x * 4 + wave;
  if (n >= N_NODES) return;
  const float* hr = h + (size_t)n * DH;
  const float* er = aggE + (size_t)n * DE;
  float h0 = hr[lane], h1 = hr[lane + 64];
  float e0 = er[lane];
  float e1 = (lane < DE - 64) ? er[lane + 64] : 0.f;

  float pm0 = h0 * Wm2[lane] + h1 * Wm2[lane + 64];
  float pm1 = h0 * Wm2[FM + lane] + h1 * Wm2[FM + lane + 64];
  float ve0 = e0 * Wm2[DIN + lane] + ((lane < DE - 64) ? e1 * Wm2[DIN + lane + 64] : 0.f);
  float ve1 = e0 * Wm2[FM + DIN + lane] + ((lane < DE - 64) ? e1 * Wm2[FM + DIN + lane + 64] : 0.f);
  float pr0 = h0 * Wr2[lane] + h1 * Wr2[lane + 64];
  float pr1 = h0 * Wr2[DH + lane] + h1 * Wr2[DH + lane + 64];

#pragma unroll
  for (int m = 32; m >= 1; m >>= 1) {
    pm0 += __shfl_xor(pm0, m, 64); pm1 += __shfl_xor(pm1, m, 64);
    ve0 += __shfl_xor(ve0, m, 64); ve1 += __shfl_xor(ve1, m, 64);
    pr0 += __shfl_xor(pr0, m, 64); pr1 += __shfl_xor(pr1, m, 64);
  }
  if (lane == 0) {
    val[n * 2 + 0] = 0.5f * (ve0 + bm2[0]) + pr0 + br2[0];
    val[n * 2 + 1] = 0.5f * (ve1 + bm2[1]) + pr1 + br2[1];
    pm[n * 2 + 0] = pm0;
    pm[n * 2 + 1] = pm1;
  }
}

__global__ void k_agg2(const int* __restrict__ row_ptr, const int* __restrict__ col_s,
                       const float* __restrict__ pm, float* __restrict__ val) {
  int n = blockIdx.x * 256 + threadIdx.x;
  if (n >= N_NODES) return;
  float a0 = 0.f, a1 = 0.f;
  int s = row_ptr[n], e = row_ptr[n + 1];
  for (int p = s; p < e; ++p) {
    int c = col_s[p];
    a0 += pm[c * 2]; a1 += pm[c * 2 + 1];
  }
  val[n * 2] += 0.5f * a0;
  val[n * 2 + 1] += 0.5f * a1;
}

__global__ void k_bnstats2(const float* __restrict__ val, float* __restrict__ s4) {
  float s0 = 0.f, q0 = 0.f, s1 = 0.f, q1 = 0.f;
  for (int n = blockIdx.x * 256 + threadIdx.x; n < N_NODES; n += gridDim.x * 256) {
    float v0 = val[n * 2], v1 = val[n * 2 + 1];
    s0 += v0; q0 += v0 * v0; s1 += v1; q1 += v1 * v1;
  }
  __shared__ float b[256][4];
  b[threadIdx.x][0] = s0; b[threadIdx.x][1] = q0;
  b[threadIdx.x][2] = s1; b[threadIdx.x][3] = q1;
  __syncthreads();
  for (int off = 128; off >= 1; off >>= 1) {
    if (threadIdx.x < off)
      for (int j = 0; j < 4; ++j) b[threadIdx.x][j] += b[threadIdx.x + off][j];
    __syncthreads();
  }
  if (threadIdx.x == 0)
    for (int j = 0; j < 4; ++j) atomicAdd(&s4[j], b[0][j]);
}

__global__ void k_final(const float* __restrict__ val, const float* __restrict__ s4,
                        const float* __restrict__ g2, const float* __restrict__ be2,
                        float* __restrict__ out) {
  int n = blockIdx.x * 256 + threadIdx.x;
  if (n >= N_NODES) return;
  float mu0 = s4[0] * (1.f / N_NODES), var0 = s4[1] * (1.f / N_NODES) - mu0 * mu0;
  float mu1 = s4[2] * (1.f / N_NODES), var1 = s4[3] * (1.f / N_NODES) - mu1 * mu1;
  float y0 = (val[n * 2] - mu0) * rsqrtf(var0 + BN_EPS) * g2[0] + be2[0];
  float y1 = (val[n * 2 + 1] - mu1) * rsqrtf(var1 + BN_EPS) * g2[1] + be2[1];
  float m = fmaxf(y0, y1);
  float lse = m + __logf(__expf(y0 - m) + __expf(y1 - m));
  out[n * 2] = y0 - lse;
  out[n * 2 + 1] = y1 - lse;
}

// ---------------- launch ----------------
extern "C" void kernel_launch(void* const* d_in, const int* in_sizes, int n_in,
                              void* d_out, int out_size, void* d_ws, size_t ws_size,
                              hipStream_t stream) {
  (void)in_sizes; (void)n_in; (void)out_size; (void)ws_size;
  const float* x        = (const float*)d_in[0];
  const int*   eidx     = (const int*)d_in[1];
  const int*   row      = eidx;
  const int*   col      = eidx + N_EDGES;
  const int*   attr     = (const int*)d_in[2];
  const int*   tim      = (const int*)d_in[3];
  const int*   dire     = (const int*)d_in[4];
  const float* emb_type = (const float*)d_in[5];
  const float* emb_dir  = (const float*)d_in[6];
  const float* w_t      = (const float*)d_in[7];
  const float* b_t      = (const float*)d_in[8];
  const float* Wm[3] = {(const float*)d_in[9],  (const float*)d_in[15], (const float*)d_in[21]};
  const float* bm[3] = {(const float*)d_in[10], (const float*)d_in[16], (const float*)d_in[22]};
  const float* Wr[3] = {(const float*)d_in[11], (const float*)d_in[17], (const float*)d_in[23]};
  const float* br[3] = {(const float*)d_in[12], (const float*)d_in[18], (const float*)d_in[24]};
  const float* g[3]  = {(const float*)d_in[13], (const float*)d_in[19], (const float*)d_in[25]};
  const float* be[3] = {(const float*)d_in[14], (const float*)d_in[20], (const float*)d_in[26]};
  float* out = (float*)d_out;

  // workspace layout
  char* p = (char*)d_ws;
  float* aggE = (float*)p;  p += sizeof(float) * (size_t)N_NODES * DE;
  float* aggH = (float*)p;  p += sizeof(float) * (size_t)N_NODES * DH;
  float* hA   = (float*)p;  p += sizeof(float) * (size_t)N_NODES * DH;
  float* val  = (float*)p;  p += sizeof(float) * (size_t)N_NODES * 2;
  float* pmb  = (float*)p;  p += sizeof(float) * (size_t)N_NODES * 2;
  float* WmHT[2]; float* WmET[2]; float* WrT[2]; float* bv[2];
  for (int l = 0; l < 2; ++l) {
    WmHT[l] = (float*)p; p += sizeof(float) * DIN * DH;   // 128x128
    WmET[l] = (float*)p; p += sizeof(float) * DE * DH;    // 100x128
    WrT[l]  = (float*)p; p += sizeof(float) * DIN * DH;   // 128x128
    bv[l]   = (float*)p; p += sizeof(float) * DH;
  }
  float* stats = (float*)p; p += sizeof(float) * 520;
  float* tlog  = (float*)p; p += sizeof(float) * N_EDGES;
  int* counts  = (int*)p;   p += sizeof(int) * N_NODES;
  int* cursor  = (int*)p;   p += sizeof(int) * N_NODES;
  int* row_ptr = (int*)p;   p += sizeof(int) * (N_NODES + 1);
  int* col_s   = (int*)p;   p += sizeof(int) * N_EDGES;
  int* eid_s   = (int*)p;   p += sizeof(int) * N_EDGES;
  int* incl    = (int*)p;   p += sizeof(int) * N_NODES;
  int* bsum    = (int*)p;   p += sizeof(int) * SCAN_NB;
  int* boff    = (int*)p;   p += sizeof(int) * SCAN_NB;

  const int EB = (N_EDGES + 255) / 256;      // 3125
  const int NB = (N_NODES + 255) / 256;      // 196

  hipMemsetAsync(counts, 0, sizeof(int) * N_NODES, stream);
  hipMemsetAsync(stats, 0, sizeof(float) * 520, stream);

  // CSR (hierarchical scan)
  k_count<<<EB, 256, 0, stream>>>(row, counts);
  k_scan_a<<<SCAN_NB, 256, 0, stream>>>(counts, incl, bsum);
  k_scan_b<<<1, 256, 0, stream>>>(bsum, boff, row_ptr);
  k_scan_c<<<SCAN_NB, 256, 0, stream>>>(incl, counts, boff, row_ptr, cursor);
  k_fill<<<EB, 256, 0, stream>>>(row, col, cursor, col_s, eid_s);
  k_tlog<<<EB, 256, 0, stream>>>(tim, tlog);

  // weight prep
  for (int l = 0; l < 2; ++l) {
    k_transpose<<<(DIN * DH + 255) / 256, 256, 0, stream>>>(Wm[l], WmHT[l], DH, DIN, FM, 0, 0.5f);
    k_transpose<<<(DE * DH + 255) / 256, 256, 0, stream>>>(Wm[l], WmET[l], DH, DE, FM, DIN, 0.5f);
    k_transpose<<<(DIN * DH + 255) / 256, 256, 0, stream>>>(Wr[l], WrT[l], DH, DIN, DIN, 0, 1.0f);
    k_bias<<<1, 128, 0, stream>>>(bm[l], br[l], bv[l]);
  }

  // edge-feature aggregation (shared by all layers)
  k_aggE<<<N_NODES, 128, 0, stream>>>(row_ptr, eid_s, attr, dire, tlog,
                                      emb_type, emb_dir, w_t, b_t, aggE);

  const int AB = (N_NODES + 3) / 4;          // 12500
  const int GB = (N_NODES + BM - 1) / BM;    // 782
  const int XB = (N_NODES * DH + 255) / 256; // 25000

  // layer 0: in x -> hA
  k_aggH<<<AB, 256, 0, stream>>>(x, row_ptr, col_s, aggH);
  k_gemm<<<GB, 256, 0, stream>>>(aggH, WmHT[0], aggE, WmET[0], x, WrT[0], bv[0], hA);
  k_bnstats<<<256, 256, 0, stream>>>(hA, stats);
  k_bnapply<<<XB, 256, 0, stream>>>(hA, stats, g[0], be[0], 1);

  // layer 1: hA -> hA
  k_aggH<<<AB, 256, 0, stream>>>(hA, row_ptr, col_s, aggH);
  k_gemm<<<GB, 256, 0, stream>>>(aggH, WmHT[1], aggE, WmET[1], hA, WrT[1], bv[1], hA);
  k_bnstats<<<256, 256, 0, stream>>>(hA, stats + 256);
  k_bnapply<<<XB, 256, 0, stream>>>(hA, stats + 256, g[1], be[1], 1);

  // layer 2: project-first (dout=2), then aggregate 2-dim
  k_l2_dense<<<AB, 256, 0, stream>>>(hA, aggE, Wm[2], bm[2], Wr[2], br[2], val, pmb);
  k_agg2<<<NB, 256, 0, stream>>>(row_ptr, col_s, pmb, val);
  k_bnstats2<<<64, 256, 0, stream>>>(val, stats + 512);
  k_final<<<NB, 256, 0, stream>>>(val, stats + 512, g[2], be[2], out);
}

// Round 3
// 607.153 us; speedup vs baseline: 1.5900x; 1.2429x over previous
//
#include <hip/hip_runtime.h>
#include <math.h>

#define N_NODES 50000
#define N_EDGES 800000
#define DIN 128
#define DH 128
#define EA_C 50
#define TC_C 50
#define DE 100
#define FM 228      // DIN + DE
#define GK 384      // unified K: 128 aggH + 128 h + 100 aggE + 28 pad
#define BN_EPS 1e-5f
#define SCAN_NB ((N_NODES + 255) / 256)   // 196

typedef __attribute__((ext_vector_type(8))) short short8;
typedef __attribute__((ext_vector_type(4))) float f32x4;
typedef unsigned int u32;
typedef unsigned short u16;

// ---- bf16 hi/lo packing: u32 = hi | (lo << 16); value = bf2f(hi)+bf2f(lo) ----
__device__ inline u16 f2bf(float f) {
  u32 u = __float_as_uint(f);
  u32 r = (u + 0x7fffu + ((u >> 16) & 1u)) >> 16;
  return (u16)r;
}
__device__ inline float bf2f(u16 h) { return __uint_as_float(((u32)h) << 16); }
__device__ inline u32 pack_hl(float v) {
  u16 hi = f2bf(v);
  u16 lo = f2bf(v - bf2f(hi));
  return (u32)hi | ((u32)lo << 16);
}
__device__ inline float unpack_hl(u32 p) {
  return bf2f((u16)(p & 0xffffu)) + bf2f((u16)(p >> 16));
}

// ---------------- CSR build ----------------
__global__ void k_count(const int* __restrict__ row, int* __restrict__ counts) {
  int e = blockIdx.x * 256 + threadIdx.x;
  if (e < N_EDGES) atomicAdd(&counts[row[e]], 1);
}

__global__ void k_scan_a(const int* __restrict__ counts, int* __restrict__ incl,
                         int* __restrict__ bsum) {
  __shared__ int buf[256];
  int i = blockIdx.x * 256 + threadIdx.x;
  int v = (i < N_NODES) ? counts[i] : 0;
  buf[threadIdx.x] = v;
  __syncthreads();
#pragma unroll
  for (int off = 1; off < 256; off <<= 1) {
    int t = (threadIdx.x >= off) ? buf[threadIdx.x - off] : 0;
    __syncthreads();
    buf[threadIdx.x] += t;
    __syncthreads();
  }
  if (i < N_NODES) incl[i] = buf[threadIdx.x];
  if (threadIdx.x == 255) bsum[blockIdx.x] = buf[255];
}

__global__ void k_scan_b(const int* __restrict__ bsum, int* __restrict__ boff,
                         int* __restrict__ row_ptr) {
  __shared__ int buf[256];
  int v = (threadIdx.x < SCAN_NB) ? bsum[threadIdx.x] : 0;
  buf[threadIdx.x] = v;
  __syncthreads();
#pragma unroll
  for (int off = 1; off < 256; off <<= 1) {
    int t = (threadIdx.x >= off) ? buf[threadIdx.x - off] : 0;
    __syncthreads();
    buf[threadIdx.x] += t;
    __syncthreads();
  }
  if (threadIdx.x < SCAN_NB) boff[threadIdx.x] = buf[threadIdx.x] - v;
  if (threadIdx.x == 255) row_ptr[N_NODES] = buf[255];
}

__global__ void k_scan_c(const int* __restrict__ incl, const int* __restrict__ counts,
                         const int* __restrict__ boff, int* __restrict__ row_ptr,
                         int* __restrict__ cursor) {
  int i = blockIdx.x * 256 + threadIdx.x;
  if (i < N_NODES) {
    int p = incl[i] - counts[i] + boff[blockIdx.x];
    row_ptr[i] = p;
    cursor[i] = p;
  }
}

__global__ void k_fill(const int* __restrict__ row, const int* __restrict__ col,
                       int* __restrict__ cursor, int* __restrict__ col_s,
                       int* __restrict__ eid_s) {
  int e = blockIdx.x * 256 + threadIdx.x;
  if (e < N_EDGES) {
    int r = row[e];
    int slot = atomicAdd(&cursor[r], 1);
    col_s[slot] = col[e];
    eid_s[slot] = e;
  }
}

__global__ void k_tlog(const int* __restrict__ tim, float* __restrict__ tlog) {
  int e = blockIdx.x * 256 + threadIdx.x;
  if (e < N_EDGES) tlog[e] = __logf((float)tim[e] + 1.0f);
}

// ---------------- x -> A cols 128..255 (hi/lo) ----------------
__global__ void k_conv_x(const float* __restrict__ x, u32* __restrict__ A) {
  int idx = blockIdx.x * 256 + threadIdx.x;
  if (idx >= N_NODES * DH) return;
  int n = idx >> 7, c = idx & 127;
  A[(size_t)n * GK + 128 + c] = pack_hl(x[idx]);
}

// ---------------- edge-embedding aggregation -> A cols 256..383 ----------------
__global__ void k_aggE(const int* __restrict__ row_ptr, const int* __restrict__ eid_s,
                       const int* __restrict__ attr, const int* __restrict__ dire,
                       const float* __restrict__ tlog,
                       const float* __restrict__ emb_type, const float* __restrict__ emb_dir,
                       const float* __restrict__ w_t, const float* __restrict__ b_t,
                       u32* __restrict__ A) {
  int n = blockIdx.x;
  int wave = threadIdx.x >> 6;
  int lane = threadIdx.x & 63;
  if (lane >= EA_C) {
    // zero pad cols 356..383 (28 cols split across the two waves)
    int col = (wave == 0) ? (370 + lane - EA_C) : (356 + lane - EA_C);
    A[(size_t)n * GK + col] = 0u;
    return;
  }
  int s = row_ptr[n], epos = row_ptr[n + 1];
  float acc = 0.f;
  if (wave == 0) {
    for (int p = s; p < epos; ++p) {
      int e = eid_s[p];
      acc += emb_type[attr[e] * EA_C + lane] + emb_dir[dire[e] * EA_C + lane];
    }
    A[(size_t)n * GK + 256 + lane] = pack_hl(acc);
  } else {
    float w = w_t[lane], b = b_t[lane];
    for (int p = s; p < epos; ++p) {
      int e = eid_s[p];
      acc += __cosf(tlog[e] * w + b);
    }
    A[(size_t)n * GK + 256 + EA_C + lane] = pack_hl(acc);
  }
}

// ---------------- neighbor aggregation: A cols 128..255 -> A cols 0..127 ----
__global__ void k_aggH(const int* __restrict__ row_ptr, const int* __restrict__ col_s,
                       u32* __restrict__ A) {
  int wave = threadIdx.x >> 6, lane = threadIdx.x & 63;
  int n = blockIdx.x * 4 + wave;
  if (n >= N_NODES) return;
  int s = row_ptr[n], epos = row_ptr[n + 1];
  float ax = 0.f, ay = 0.f;
  for (int p = s; p < epos; ++p) {
    int c = col_s[p];
    uint2 v = *reinterpret_cast<const uint2*>(A + (size_t)c * GK + 128 + 2 * lane);
    ax += unpack_hl(v.x); ay += unpack_hl(v.y);
  }
  uint2 o; o.x = pack_hl(ax); o.y = pack_hl(ay);
  *reinterpret_cast<uint2*>(A + (size_t)n * GK + 2 * lane) = o;
}

// ---------------- weight prep: WT2[col][k] packed hi/lo ----------------
// k<128: 0.5*Wm[:, k]; 128<=k<256: Wr[:, k-128]; 256<=k<356: 0.5*Wm[:, k-128]; else 0
__global__ void k_wprep(const float* __restrict__ Wm, const float* __restrict__ Wr,
                        u32* __restrict__ WT2) {
  int idx = blockIdx.x * 256 + threadIdx.x;
  if (idx >= DH * GK) return;
  int o = idx / GK, k = idx - o * GK;
  float v;
  if (k < 128) v = 0.5f * Wm[o * FM + k];
  else if (k < 256) v = Wr[o * DIN + (k - 128)];
  else if (k < 356) v = 0.5f * Wm[o * FM + (k - 128)];
  else v = 0.f;
  WT2[idx] = pack_hl(v);
}

__global__ void k_bias(const float* __restrict__ bm, const float* __restrict__ br,
                       float* __restrict__ bv) {
  int o = threadIdx.x;
  if (o < DH) bv[o] = 0.5f * bm[o] + br[o];
}

// ---------------- MFMA GEMM: out[N,128] = unpack(A) @ unpack(W)^T' + bv ------
// A: [N][384] packed hi/lo. W (WT2): [128 col][384 k] packed hi/lo.
// block 256 = 4 waves; wave w covers rows node0+w*16..+16, all 128 cols.
__global__ __launch_bounds__(256) void k_mfma(const u32* __restrict__ A,
                                              const u32* __restrict__ W,
                                              const float* __restrict__ bv,
                                              float* __restrict__ out) {
  __shared__ u16 Ah[64][32], Al[64][32];     // 4KB each
  __shared__ u16 Wh[128][32], Wl[128][32];   // 8KB each
  int tid = threadIdx.x;
  int wv = tid >> 6, ln = tid & 63;
  int node0 = blockIdx.x * 64;

  f32x4 acc[8];
#pragma unroll
  for (int nt = 0; nt < 8; ++nt) acc[nt] = (f32x4){0.f, 0.f, 0.f, 0.f};

  // staging geometry
  int ar = tid >> 2, ac = (tid & 3) * 8;        // A: 64 rows x (4 thr * 8 elems)
  int wc = tid >> 1, wk = (tid & 1) * 16;       // W: 128 cols x (2 thr * 16 elems)
  int an = node0 + ar;
  const u32* aptr = A + (size_t)an * GK + ac;
  const u32* wptr = W + (size_t)wc * GK + wk;

  // frag addresses
  const u16* afh = &Ah[(wv << 4) + (ln & 15)][(ln >> 4) * 8];
  const u16* afl = &Al[(wv << 4) + (ln & 15)][(ln >> 4) * 8];

  for (int kc = 0; kc < GK; kc += 32) {
    uint4 a0, a1;
    if (an < N_NODES) {
      a0 = *reinterpret_cast<const uint4*>(aptr + kc);
      a1 = *reinterpret_cast<const uint4*>(aptr + kc + 4);
    } else {
      a0 = make_uint4(0, 0, 0, 0); a1 = make_uint4(0, 0, 0, 0);
    }
    uint4 w0 = *reinterpret_cast<const uint4*>(wptr + kc);
    uint4 w1 = *reinterpret_cast<const uint4*>(wptr + kc + 4);
    uint4 w2 = *reinterpret_cast<const uint4*>(wptr + kc + 8);
    uint4 w3 = *reinterpret_cast<const uint4*>(wptr + kc + 12);

    __syncthreads();   // previous iteration's frag reads complete

    {
      u32 va[8] = {a0.x, a0.y, a0.z, a0.w, a1.x, a1.y, a1.z, a1.w};
      short8 h, l;
#pragma unroll
      for (int j = 0; j < 8; ++j) { h[j] = (short)(va[j] & 0xffffu); l[j] = (short)(va[j] >> 16); }
      *reinterpret_cast<short8*>(&Ah[ar][ac]) = h;
      *reinterpret_cast<short8*>(&Al[ar][ac]) = l;
    }
    {
      u32 vw[16] = {w0.x, w0.y, w0.z, w0.w, w1.x, w1.y, w1.z, w1.w,
                    w2.x, w2.y, w2.z, w2.w, w3.x, w3.y, w3.z, w3.w};
      short8 h0, l0, h1, l1;
#pragma unroll
      for (int j = 0; j < 8; ++j) {
        h0[j] = (short)(vw[j] & 0xffffu);     l0[j] = (short)(vw[j] >> 16);
        h1[j] = (short)(vw[j + 8] & 0xffffu); l1[j] = (short)(vw[j + 8] >> 16);
      }
      *reinterpret_cast<short8*>(&Wh[wc][wk]) = h0;
      *reinterpret_cast<short8*>(&Wh[wc][wk + 8]) = h1;
      *reinterpret_cast<short8*>(&Wl[wc][wk]) = l0;
      *reinterpret_cast<short8*>(&Wl[wc][wk + 8]) = l1;
    }

    __syncthreads();   // LDS writes visible

    short8 ah = *reinterpret_cast<const short8*>(afh);
    short8 al = *reinterpret_cast<const short8*>(afl);
#pragma unroll
    for (int nt = 0; nt < 8; ++nt) {
      short8 bh = *reinterpret_cast<const short8*>(&Wh[nt * 16 + (ln & 15)][(ln >> 4) * 8]);
      short8 bl = *reinterpret_cast<const short8*>(&Wl[nt * 16 + (ln & 15)][(ln >> 4) * 8]);
      acc[nt] = __builtin_amdgcn_mfma_f32_16x16x32_bf16(ah, bh, acc[nt], 0, 0, 0);
      acc[nt] = __builtin_amdgcn_mfma_f32_16x16x32_bf16(al, bh, acc[nt], 0, 0, 0);
      acc[nt] = __builtin_amdgcn_mfma_f32_16x16x32_bf16(ah, bl, acc[nt], 0, 0, 0);
    }
  }

  // epilogue: C lane layout col=lane&15, row=(lane>>4)*4+reg
  int rbase = node0 + (wv << 4) + ((ln >> 4) << 2);
  int colb = ln & 15;
#pragma unroll
  for (int nt = 0; nt < 8; ++nt) {
    int col = nt * 16 + colb;
    float bb = bv[col];
#pragma unroll
    for (int r = 0; r < 4; ++r) {
      int n = rbase + r;
      if (n < N_NODES) out[(size_t)n * DH + col] = acc[nt][r] + bb;
    }
  }
}

// ---------------- BatchNorm stats ----------------
__global__ void k_bnstats(const float* __restrict__ x, float* __restrict__ stats) {
  int c = threadIdx.x & 127;
  int half = threadIdx.x >> 7;
  float s = 0.f, q = 0.f;
  for (int r = blockIdx.x * 2 + half; r < N_NODES; r += gridDim.x * 2) {
    float v = x[(size_t)r * DH + c];
    s += v; q += v * v;
  }
  __shared__ float ls[256], lq[256];
  ls[threadIdx.x] = s; lq[threadIdx.x] = q;
  __syncthreads();
  if (half == 0) {
    s += ls[128 + c]; q += lq[128 + c];
    atomicAdd(&stats[c], s);
    atomicAdd(&stats[128 + c], q);
  }
}

// BN + ELU, write hi/lo into A cols 128..255
__global__ void k_bnapply(const float* __restrict__ x, const float* __restrict__ stats,
                          const float* __restrict__ g, const float* __restrict__ be,
                          u32* __restrict__ A) {
  int idx = blockIdx.x * 256 + threadIdx.x;
  if (idx >= N_NODES * DH) return;
  int n = idx >> 7, c = idx & 127;
  float mu = stats[c] * (1.0f / N_NODES);
  float var = stats[128 + c] * (1.0f / N_NODES) - mu * mu;
  float y = (x[idx] - mu) * rsqrtf(var + BN_EPS) * g[c] + be[c];
  y = y > 0.f ? y : expm1f(y);
  A[(size_t)n * GK + 128 + c] = pack_hl(y);
}

// ---------------- layer 2 (project-first, dout=2) ----------------
__global__ void k_l2_dense(const u32* __restrict__ A,
                           const float* __restrict__ Wm2, const float* __restrict__ bm2,
                           const float* __restrict__ Wr2, const float* __restrict__ br2,
                           float* __restrict__ val, float* __restrict__ pm) {
  int wave = threadIdx.x >> 6, lane = threadIdx.x & 63;
  int n = blockIdx.x * 4 + wave;
  if (n >= N_NODES) return;
  const u32* ar = A + (size_t)n * GK;
  float h0 = unpack_hl(ar[128 + lane]);
  float h1 = unpack_hl(ar[128 + lane + 64]);
  float e0 = unpack_hl(ar[256 + lane]);
  float e1 = (lane < DE - 64) ? unpack_hl(ar[256 + lane + 64]) : 0.f;

  float pm0 = h0 * Wm2[lane] + h1 * Wm2[lane + 64];
  float pm1 = h0 * Wm2[FM + lane] + h1 * Wm2[FM + lane + 64];
  float ve0 = e0 * Wm2[DIN + lane] + ((lane < DE - 64) ? e1 * Wm2[DIN + lane + 64] : 0.f);
  float ve1 = e0 * Wm2[FM + DIN + lane] + ((lane < DE - 64) ? e1 * Wm2[FM + DIN + lane + 64] : 0.f);
  float pr0 = h0 * Wr2[lane] + h1 * Wr2[lane + 64];
  float pr1 = h0 * Wr2[DH + lane] + h1 * Wr2[DH + lane + 64];

#pragma unroll
  for (int m = 32; m >= 1; m >>= 1) {
    pm0 += __shfl_xor(pm0, m, 64); pm1 += __shfl_xor(pm1, m, 64);
    ve0 += __shfl_xor(ve0, m, 64); ve1 += __shfl_xor(ve1, m, 64);
    pr0 += __shfl_xor(pr0, m, 64); pr1 += __shfl_xor(pr1, m, 64);
  }
  if (lane == 0) {
    val[n * 2 + 0] = 0.5f * (ve0 + bm2[0]) + pr0 + br2[0];
    val[n * 2 + 1] = 0.5f * (ve1 + bm2[1]) + pr1 + br2[1];
    pm[n * 2 + 0] = pm0;
    pm[n * 2 + 1] = pm1;
  }
}

__global__ void k_agg2(const int* __restrict__ row_ptr, const int* __restrict__ col_s,
                       const float* __restrict__ pm, float* __restrict__ val) {
  int n = blockIdx.x * 256 + threadIdx.x;
  if (n >= N_NODES) return;
  float a0 = 0.f, a1 = 0.f;
  int s = row_ptr[n], e = row_ptr[n + 1];
  for (int p = s; p < e; ++p) {
    int c = col_s[p];
    a0 += pm[c * 2]; a1 += pm[c * 2 + 1];
  }
  val[n * 2] += 0.5f * a0;
  val[n * 2 + 1] += 0.5f * a1;
}

__global__ void k_bnstats2(const float* __restrict__ val, float* __restrict__ s4) {
  float s0 = 0.f, q0 = 0.f, s1 = 0.f, q1 = 0.f;
  for (int n = blockIdx.x * 256 + threadIdx.x; n < N_NODES; n += gridDim.x * 256) {
    float v0 = val[n * 2], v1 = val[n * 2 + 1];
    s0 += v0; q0 += v0 * v0; s1 += v1; q1 += v1 * v1;
  }
  __shared__ float b[256][4];
  b[threadIdx.x][0] = s0; b[threadIdx.x][1] = q0;
  b[threadIdx.x][2] = s1; b[threadIdx.x][3] = q1;
  __syncthreads();
  for (int off = 128; off >= 1; off >>= 1) {
    if (threadIdx.x < off)
      for (int j = 0; j < 4; ++j) b[threadIdx.x][j] += b[threadIdx.x + off][j];
    __syncthreads();
  }
  if (threadIdx.x == 0)
    for (int j = 0; j < 4; ++j) atomicAdd(&s4[j], b[0][j]);
}

__global__ void k_final(const float* __restrict__ val, const float* __restrict__ s4,
                        const float* __restrict__ g2, const float* __restrict__ be2,
                        float* __restrict__ out) {
  int n = blockIdx.x * 256 + threadIdx.x;
  if (n >= N_NODES) return;
  float mu0 = s4[0] * (1.f / N_NODES), var0 = s4[1] * (1.f / N_NODES) - mu0 * mu0;
  float mu1 = s4[2] * (1.f / N_NODES), var1 = s4[3] * (1.f / N_NODES) - mu1 * mu1;
  float y0 = (val[n * 2] - mu0) * rsqrtf(var0 + BN_EPS) * g2[0] + be2[0];
  float y1 = (val[n * 2 + 1] - mu1) * rsqrtf(var1 + BN_EPS) * g2[1] + be2[1];
  float m = fmaxf(y0, y1);
  float lse = m + __logf(__expf(y0 - m) + __expf(y1 - m));
  out[n * 2] = y0 - lse;
  out[n * 2 + 1] = y1 - lse;
}

// ---------------- launch ----------------
extern "C" void kernel_launch(void* const* d_in, const int* in_sizes, int n_in,
                              void* d_out, int out_size, void* d_ws, size_t ws_size,
                              hipStream_t stream) {
  (void)in_sizes; (void)n_in; (void)out_size; (void)ws_size;
  const float* x        = (const float*)d_in[0];
  const int*   eidx     = (const int*)d_in[1];
  const int*   row      = eidx;
  const int*   col      = eidx + N_EDGES;
  const int*   attr     = (const int*)d_in[2];
  const int*   tim      = (const int*)d_in[3];
  const int*   dire     = (const int*)d_in[4];
  const float* emb_type = (const float*)d_in[5];
  const float* emb_dir  = (const float*)d_in[6];
  const float* w_t      = (const float*)d_in[7];
  const float* b_t      = (const float*)d_in[8];
  const float* Wm[3] = {(const float*)d_in[9],  (const float*)d_in[15], (const float*)d_in[21]};
  const float* bm[3] = {(const float*)d_in[10], (const float*)d_in[16], (const float*)d_in[22]};
  const float* Wr[3] = {(const float*)d_in[11], (const float*)d_in[17], (const float*)d_in[23]};
  const float* br[3] = {(const float*)d_in[12], (const float*)d_in[18], (const float*)d_in[24]};
  const float* g[3]  = {(const float*)d_in[13], (const float*)d_in[19], (const float*)d_in[25]};
  const float* be[3] = {(const float*)d_in[14], (const float*)d_in[20], (const float*)d_in[26]};
  float* out = (float*)d_out;

  // workspace layout
  char* p = (char*)d_ws;
  u32* A     = (u32*)p;   p += sizeof(u32) * (size_t)N_NODES * GK;   // 76.8 MB
  float* gout = (float*)p; p += sizeof(float) * (size_t)N_NODES * DH; // 25.6 MB
  u32* WT2[2];
  WT2[0] = (u32*)p; p += sizeof(u32) * DH * GK;
  WT2[1] = (u32*)p; p += sizeof(u32) * DH * GK;
  float* bv[2];
  bv[0] = (float*)p; p += sizeof(float) * DH;
  bv[1] = (float*)p; p += sizeof(float) * DH;
  float* val  = (float*)p;  p += sizeof(float) * (size_t)N_NODES * 2;
  float* pmb  = (float*)p;  p += sizeof(float) * (size_t)N_NODES * 2;
  float* stats = (float*)p; p += sizeof(float) * 520;
  float* tlog  = (float*)p; p += sizeof(float) * N_EDGES;
  int* counts  = (int*)p;   p += sizeof(int) * N_NODES;
  int* cursor  = (int*)p;   p += sizeof(int) * N_NODES;
  int* row_ptr = (int*)p;   p += sizeof(int) * (N_NODES + 1);
  int* col_s   = (int*)p;   p += sizeof(int) * N_EDGES;
  int* eid_s   = (int*)p;   p += sizeof(int) * N_EDGES;
  int* incl    = (int*)p;   p += sizeof(int) * N_NODES;
  int* bsum    = (int*)p;   p += sizeof(int) * SCAN_NB;
  int* boff    = (int*)p;   p += sizeof(int) * SCAN_NB;

  const int EB = (N_EDGES + 255) / 256;      // 3125
  const int NB = (N_NODES + 255) / 256;      // 196
  const int AB = (N_NODES + 3) / 4;          // 12500
  const int GB = (N_NODES + 63) / 64;        // 782
  const int XB = (N_NODES * DH + 255) / 256; // 25000
  const int WB = (DH * GK + 255) / 256;      // 192

  hipMemsetAsync(counts, 0, sizeof(int) * N_NODES, stream);
  hipMemsetAsync(stats, 0, sizeof(float) * 520, stream);

  // CSR
  k_count<<<EB, 256, 0, stream>>>(row, counts);
  k_scan_a<<<SCAN_NB, 256, 0, stream>>>(counts, incl, bsum);
  k_scan_b<<<1, 256, 0, stream>>>(bsum, boff, row_ptr);
  k_scan_c<<<SCAN_NB, 256, 0, stream>>>(incl, counts, boff, row_ptr, cursor);
  k_fill<<<EB, 256, 0, stream>>>(row, col, cursor, col_s, eid_s);
  k_tlog<<<EB, 256, 0, stream>>>(tim, tlog);

  // weight prep
  for (int l = 0; l < 2; ++l) {
    k_wprep<<<WB, 256, 0, stream>>>(Wm[l], Wr[l], WT2[l]);
    k_bias<<<1, 128, 0, stream>>>(bm[l], br[l], bv[l]);
  }

  // x -> A h-region; edge features -> A e-region (+pad)
  k_conv_x<<<XB, 256, 0, stream>>>(x, A);
  k_aggE<<<N_NODES, 128, 0, stream>>>(row_ptr, eid_s, attr, dire, tlog,
                                      emb_type, emb_dir, w_t, b_t, A);

  // layer 0
  k_aggH<<<AB, 256, 0, stream>>>(row_ptr, col_s, A);
  k_mfma<<<GB, 256, 0, stream>>>(A, WT2[0], bv[0], gout);
  k_bnstats<<<256, 256, 0, stream>>>(gout, stats);
  k_bnapply<<<XB, 256, 0, stream>>>(gout, stats, g[0], be[0], A);

  // layer 1
  k_aggH<<<AB, 256, 0, stream>>>(row_ptr, col_s, A);
  k_mfma<<<GB, 256, 0, stream>>>(A, WT2[1], bv[1], gout);
  k_bnstats<<<256, 256, 0, stream>>>(gout, stats + 256);
  k_bnapply<<<XB, 256, 0, stream>>>(gout, stats + 256, g[1], be[1], A);

  // layer 2
  k_l2_dense<<<AB, 256, 0, stream>>>(A, Wm[2], bm[2], Wr[2], br[2], val, pmb);
  k_agg2<<<NB, 256, 0, stream>>>(row_ptr, col_s, pmb, val);
  k_bnstats2<<<64, 256, 0, stream>>>(val, stats + 512);
  k_final<<<NB, 256, 0, stream>>>(val, stats + 512, g[2], be[2], out);
}

// Round 4
// 527.288 us; speedup vs baseline: 1.8309x; 1.1515x over previous
//
#include <hip/hip_runtime.h>
#include <math.h>

#define N_NODES 50000
#define N_EDGES 800000
#define DIN 128
#define DH 128
#define EA_C 50
#define TC_C 50
#define DE 100
#define FM 228      // DIN + DE
#define GK 384      // unified K: 128 aggH + 128 h + 100 aggE + 28 pad
#define BN_EPS 1e-5f
#define SCAN_NB ((N_NODES + 255) / 256)   // 196

typedef __attribute__((ext_vector_type(8))) short short8;
typedef __attribute__((ext_vector_type(4))) float f32x4;
typedef unsigned int u32;
typedef unsigned short u16;

// ---- bf16 hi/lo packing: u32 = hi | (lo << 16); value = bf2f(hi)+bf2f(lo) ----
__device__ inline u16 f2bf(float f) {
  u32 u = __float_as_uint(f);
  u32 r = (u + 0x7fffu + ((u >> 16) & 1u)) >> 16;
  return (u16)r;
}
__device__ inline float bf2f(u16 h) { return __uint_as_float(((u32)h) << 16); }
__device__ inline u32 pack_hl(float v) {
  u16 hi = f2bf(v);
  u16 lo = f2bf(v - bf2f(hi));
  return (u32)hi | ((u32)lo << 16);
}
__device__ inline float unpack_hl(u32 p) {
  return bf2f((u16)(p & 0xffffu)) + bf2f((u16)(p >> 16));
}

// ---------------- CSR build ----------------
__global__ void k_count(const int* __restrict__ row, int* __restrict__ counts) {
  int e = blockIdx.x * 256 + threadIdx.x;
  if (e < N_EDGES) atomicAdd(&counts[row[e]], 1);
}

__global__ void k_scan_a(const int* __restrict__ counts, int* __restrict__ incl,
                         int* __restrict__ bsum) {
  __shared__ int buf[256];
  int i = blockIdx.x * 256 + threadIdx.x;
  int v = (i < N_NODES) ? counts[i] : 0;
  buf[threadIdx.x] = v;
  __syncthreads();
#pragma unroll
  for (int off = 1; off < 256; off <<= 1) {
    int t = (threadIdx.x >= off) ? buf[threadIdx.x - off] : 0;
    __syncthreads();
    buf[threadIdx.x] += t;
    __syncthreads();
  }
  if (i < N_NODES) incl[i] = buf[threadIdx.x];
  if (threadIdx.x == 255) bsum[blockIdx.x] = buf[255];
}

__global__ void k_scan_b(const int* __restrict__ bsum, int* __restrict__ boff,
                         int* __restrict__ row_ptr) {
  __shared__ int buf[256];
  int v = (threadIdx.x < SCAN_NB) ? bsum[threadIdx.x] : 0;
  buf[threadIdx.x] = v;
  __syncthreads();
#pragma unroll
  for (int off = 1; off < 256; off <<= 1) {
    int t = (threadIdx.x >= off) ? buf[threadIdx.x - off] : 0;
    __syncthreads();
    buf[threadIdx.x] += t;
    __syncthreads();
  }
  if (threadIdx.x < SCAN_NB) boff[threadIdx.x] = buf[threadIdx.x] - v;
  if (threadIdx.x == 255) row_ptr[N_NODES] = buf[255];
}

__global__ void k_scan_c(const int* __restrict__ incl, const int* __restrict__ counts,
                         const int* __restrict__ boff, int* __restrict__ row_ptr,
                         int* __restrict__ cursor) {
  int i = blockIdx.x * 256 + threadIdx.x;
  if (i < N_NODES) {
    int p = incl[i] - counts[i] + boff[blockIdx.x];
    row_ptr[i] = p;
    cursor[i] = p;
  }
}

// fill CSR: scatter col + edge payload (attr|dir, log(t+1)) into CSR order
__global__ void k_fill(const int* __restrict__ row, const int* __restrict__ col,
                       const int* __restrict__ attr, const int* __restrict__ dire,
                       const int* __restrict__ tim,
                       int* __restrict__ cursor, int* __restrict__ col_s,
                       int* __restrict__ ad_s, float* __restrict__ tlog_s) {
  int e = blockIdx.x * 256 + threadIdx.x;
  if (e < N_EDGES) {
    int r = row[e];
    int slot = atomicAdd(&cursor[r], 1);
    col_s[slot] = col[e];
    ad_s[slot] = attr[e] | (dire[e] << 16);
    tlog_s[slot] = __logf((float)tim[e] + 1.0f);
  }
}

// ---------------- x -> A cols 128..255 (hi/lo) ----------------
__global__ void k_conv_x(const float* __restrict__ x, u32* __restrict__ A) {
  int idx = blockIdx.x * 256 + threadIdx.x;
  if (idx >= N_NODES * DH) return;
  int n = idx >> 7, c = idx & 127;
  A[(size_t)n * GK + 128 + c] = pack_hl(x[idx]);
}

// ---------------- edge-embedding aggregation -> A cols 256..383 ----------------
// CSR-ordered payload: sequential reads of ad_s / tlog_s within node segment.
__global__ void k_aggE(const int* __restrict__ row_ptr, const int* __restrict__ ad_s,
                       const float* __restrict__ tlog_s,
                       const float* __restrict__ emb_type, const float* __restrict__ emb_dir,
                       const float* __restrict__ w_t, const float* __restrict__ b_t,
                       u32* __restrict__ A) {
  int n = blockIdx.x;
  int wave = threadIdx.x >> 6;
  int lane = threadIdx.x & 63;
  if (lane >= EA_C) {
    int col = (wave == 0) ? (370 + lane - EA_C) : (356 + lane - EA_C);
    A[(size_t)n * GK + col] = 0u;
    return;
  }
  int s = row_ptr[n], epos = row_ptr[n + 1];
  float acc = 0.f;
  if (wave == 0) {
    for (int p = s; p < epos; ++p) {
      int ad = ad_s[p];
      acc += emb_type[(ad & 0xffff) * EA_C + lane] + emb_dir[(ad >> 16) * EA_C + lane];
    }
    A[(size_t)n * GK + 256 + lane] = pack_hl(acc);
  } else {
    float w = w_t[lane], b = b_t[lane];
    for (int p = s; p < epos; ++p) {
      acc += __cosf(tlog_s[p] * w + b);
    }
    A[(size_t)n * GK + 256 + EA_C + lane] = pack_hl(acc);
  }
}

// ---------------- neighbor aggregation: A cols 128..255 -> A cols 0..127 ----
__global__ void k_aggH(const int* __restrict__ row_ptr, const int* __restrict__ col_s,
                       u32* __restrict__ A) {
  int wave = threadIdx.x >> 6, lane = threadIdx.x & 63;
  int n = blockIdx.x * 4 + wave;
  if (n >= N_NODES) return;
  int s = row_ptr[n], epos = row_ptr[n + 1];
  float ax = 0.f, ay = 0.f;
  for (int p = s; p < epos; ++p) {
    int c = col_s[p];
    uint2 v = *reinterpret_cast<const uint2*>(A + (size_t)c * GK + 128 + 2 * lane);
    ax += unpack_hl(v.x); ay += unpack_hl(v.y);
  }
  uint2 o; o.x = pack_hl(ax); o.y = pack_hl(ay);
  *reinterpret_cast<uint2*>(A + (size_t)n * GK + 2 * lane) = o;
}

// ---------------- weight prep: WT2[col][k] packed hi/lo ----------------
__global__ void k_wprep(const float* __restrict__ Wm, const float* __restrict__ Wr,
                        u32* __restrict__ WT2) {
  int idx = blockIdx.x * 256 + threadIdx.x;
  if (idx >= DH * GK) return;
  int o = idx / GK, k = idx - o * GK;
  float v;
  if (k < 128) v = 0.5f * Wm[o * FM + k];
  else if (k < 256) v = Wr[o * DIN + (k - 128)];
  else if (k < 356) v = 0.5f * Wm[o * FM + (k - 128)];
  else v = 0.f;
  WT2[idx] = pack_hl(v);
}

__global__ void k_bias(const float* __restrict__ bm, const float* __restrict__ br,
                       float* __restrict__ bv) {
  int o = threadIdx.x;
  if (o < DH) bv[o] = 0.5f * bm[o] + br[o];
}

// ---------------- MFMA GEMM ----------------
__global__ __launch_bounds__(256) void k_mfma(const u32* __restrict__ A,
                                              const u32* __restrict__ W,
                                              const float* __restrict__ bv,
                                              float* __restrict__ out) {
  __shared__ u16 Ah[64][32], Al[64][32];
  __shared__ u16 Wh[128][32], Wl[128][32];
  int tid = threadIdx.x;
  int wv = tid >> 6, ln = tid & 63;
  int node0 = blockIdx.x * 64;

  f32x4 acc[8];
#pragma unroll
  for (int nt = 0; nt < 8; ++nt) acc[nt] = (f32x4){0.f, 0.f, 0.f, 0.f};

  int ar = tid >> 2, ac = (tid & 3) * 8;
  int wc = tid >> 1, wk = (tid & 1) * 16;
  int an = node0 + ar;
  const u32* aptr = A + (size_t)an * GK + ac;
  const u32* wptr = W + (size_t)wc * GK + wk;

  const u16* afh = &Ah[(wv << 4) + (ln & 15)][(ln >> 4) * 8];
  const u16* afl = &Al[(wv << 4) + (ln & 15)][(ln >> 4) * 8];

  for (int kc = 0; kc < GK; kc += 32) {
    uint4 a0, a1;
    if (an < N_NODES) {
      a0 = *reinterpret_cast<const uint4*>(aptr + kc);
      a1 = *reinterpret_cast<const uint4*>(aptr + kc + 4);
    } else {
      a0 = make_uint4(0, 0, 0, 0); a1 = make_uint4(0, 0, 0, 0);
    }
    uint4 w0 = *reinterpret_cast<const uint4*>(wptr + kc);
    uint4 w1 = *reinterpret_cast<const uint4*>(wptr + kc + 4);
    uint4 w2 = *reinterpret_cast<const uint4*>(wptr + kc + 8);
    uint4 w3 = *reinterpret_cast<const uint4*>(wptr + kc + 12);

    __syncthreads();

    {
      u32 va[8] = {a0.x, a0.y, a0.z, a0.w, a1.x, a1.y, a1.z, a1.w};
      short8 h, l;
#pragma unroll
      for (int j = 0; j < 8; ++j) { h[j] = (short)(va[j] & 0xffffu); l[j] = (short)(va[j] >> 16); }
      *reinterpret_cast<short8*>(&Ah[ar][ac]) = h;
      *reinterpret_cast<short8*>(&Al[ar][ac]) = l;
    }
    {
      u32 vw[16] = {w0.x, w0.y, w0.z, w0.w, w1.x, w1.y, w1.z, w1.w,
                    w2.x, w2.y, w2.z, w2.w, w3.x, w3.y, w3.z, w3.w};
      short8 h0, l0, h1, l1;
#pragma unroll
      for (int j = 0; j < 8; ++j) {
        h0[j] = (short)(vw[j] & 0xffffu);     l0[j] = (short)(vw[j] >> 16);
        h1[j] = (short)(vw[j + 8] & 0xffffu); l1[j] = (short)(vw[j + 8] >> 16);
      }
      *reinterpret_cast<short8*>(&Wh[wc][wk]) = h0;
      *reinterpret_cast<short8*>(&Wh[wc][wk + 8]) = h1;
      *reinterpret_cast<short8*>(&Wl[wc][wk]) = l0;
      *reinterpret_cast<short8*>(&Wl[wc][wk + 8]) = l1;
    }

    __syncthreads();

    short8 ah = *reinterpret_cast<const short8*>(afh);
    short8 al = *reinterpret_cast<const short8*>(afl);
#pragma unroll
    for (int nt = 0; nt < 8; ++nt) {
      short8 bh = *reinterpret_cast<const short8*>(&Wh[nt * 16 + (ln & 15)][(ln >> 4) * 8]);
      short8 bl = *reinterpret_cast<const short8*>(&Wl[nt * 16 + (ln & 15)][(ln >> 4) * 8]);
      acc[nt] = __builtin_amdgcn_mfma_f32_16x16x32_bf16(ah, bh, acc[nt], 0, 0, 0);
      acc[nt] = __builtin_amdgcn_mfma_f32_16x16x32_bf16(al, bh, acc[nt], 0, 0, 0);
      acc[nt] = __builtin_amdgcn_mfma_f32_16x16x32_bf16(ah, bl, acc[nt], 0, 0, 0);
    }
  }

  int rbase = node0 + (wv << 4) + ((ln >> 4) << 2);
  int colb = ln & 15;
#pragma unroll
  for (int nt = 0; nt < 8; ++nt) {
    int col = nt * 16 + colb;
    float bb = bv[col];
#pragma unroll
    for (int r = 0; r < 4; ++r) {
      int n = rbase + r;
      if (n < N_NODES) out[(size_t)n * DH + col] = acc[nt][r] + bb;
    }
  }
}

// ---------------- BatchNorm stats ----------------
__global__ void k_bnstats(const float* __restrict__ x, float* __restrict__ stats) {
  int c = threadIdx.x & 127;
  int half = threadIdx.x >> 7;
  float s = 0.f, q = 0.f;
  for (int r = blockIdx.x * 2 + half; r < N_NODES; r += gridDim.x * 2) {
    float v = x[(size_t)r * DH + c];
    s += v; q += v * v;
  }
  __shared__ float ls[256], lq[256];
  ls[threadIdx.x] = s; lq[threadIdx.x] = q;
  __syncthreads();
  if (half == 0) {
    s += ls[128 + c]; q += lq[128 + c];
    atomicAdd(&stats[c], s);
    atomicAdd(&stats[128 + c], q);
  }
}

__global__ void k_bnapply(const float* __restrict__ x, const float* __restrict__ stats,
                          const float* __restrict__ g, const float* __restrict__ be,
                          u32* __restrict__ A) {
  int idx = blockIdx.x * 256 + threadIdx.x;
  if (idx >= N_NODES * DH) return;
  int n = idx >> 7, c = idx & 127;
  float mu = stats[c] * (1.0f / N_NODES);
  float var = stats[128 + c] * (1.0f / N_NODES) - mu * mu;
  float y = (x[idx] - mu) * rsqrtf(var + BN_EPS) * g[c] + be[c];
  y = y > 0.f ? y : expm1f(y);
  A[(size_t)n * GK + 128 + c] = pack_hl(y);
}

// ---------------- layer 2 (project-first, dout=2) ----------------
__global__ void k_l2_dense(const u32* __restrict__ A,
                           const float* __restrict__ Wm2, const float* __restrict__ bm2,
                           const float* __restrict__ Wr2, const float* __restrict__ br2,
                           float* __restrict__ val, float* __restrict__ pm) {
  int wave = threadIdx.x >> 6, lane = threadIdx.x & 63;
  int n = blockIdx.x * 4 + wave;
  if (n >= N_NODES) return;
  const u32* ar = A + (size_t)n * GK;
  float h0 = unpack_hl(ar[128 + lane]);
  float h1 = unpack_hl(ar[128 + lane + 64]);
  float e0 = unpack_hl(ar[256 + lane]);
  float e1 = (lane < DE - 64) ? unpack_hl(ar[256 + lane + 64]) : 0.f;

  float pm0 = h0 * Wm2[lane] + h1 * Wm2[lane + 64];
  float pm1 = h0 * Wm2[FM + lane] + h1 * Wm2[FM + lane + 64];
  float ve0 = e0 * Wm2[DIN + lane] + ((lane < DE - 64) ? e1 * Wm2[DIN + lane + 64] : 0.f);
  float ve1 = e0 * Wm2[FM + DIN + lane] + ((lane < DE - 64) ? e1 * Wm2[FM + DIN + lane + 64] : 0.f);
  float pr0 = h0 * Wr2[lane] + h1 * Wr2[lane + 64];
  float pr1 = h0 * Wr2[DH + lane] + h1 * Wr2[DH + lane + 64];

#pragma unroll
  for (int m = 32; m >= 1; m >>= 1) {
    pm0 += __shfl_xor(pm0, m, 64); pm1 += __shfl_xor(pm1, m, 64);
    ve0 += __shfl_xor(ve0, m, 64); ve1 += __shfl_xor(ve1, m, 64);
    pr0 += __shfl_xor(pr0, m, 64); pr1 += __shfl_xor(pr1, m, 64);
  }
  if (lane == 0) {
    val[n * 2 + 0] = 0.5f * (ve0 + bm2[0]) + pr0 + br2[0];
    val[n * 2 + 1] = 0.5f * (ve1 + bm2[1]) + pr1 + br2[1];
    pm[n * 2 + 0] = pm0;
    pm[n * 2 + 1] = pm1;
  }
}

__global__ void k_agg2(const int* __restrict__ row_ptr, const int* __restrict__ col_s,
                       const float* __restrict__ pm, float* __restrict__ val) {
  int n = blockIdx.x * 256 + threadIdx.x;
  if (n >= N_NODES) return;
  float a0 = 0.f, a1 = 0.f;
  int s = row_ptr[n], e = row_ptr[n + 1];
  for (int p = s; p < e; ++p) {
    int c = col_s[p];
    a0 += pm[c * 2]; a1 += pm[c * 2 + 1];
  }
  val[n * 2] += 0.5f * a0;
  val[n * 2 + 1] += 0.5f * a1;
}

__global__ void k_bnstats2(const float* __restrict__ val, float* __restrict__ s4) {
  float s0 = 0.f, q0 = 0.f, s1 = 0.f, q1 = 0.f;
  for (int n = blockIdx.x * 256 + threadIdx.x; n < N_NODES; n += gridDim.x * 256) {
    float v0 = val[n * 2], v1 = val[n * 2 + 1];
    s0 += v0; q0 += v0 * v0; s1 += v1; q1 += v1 * v1;
  }
  __shared__ float b[256][4];
  b[threadIdx.x][0] = s0; b[threadIdx.x][1] = q0;
  b[threadIdx.x][2] = s1; b[threadIdx.x][3] = q1;
  __syncthreads();
  for (int off = 128; off >= 1; off >>= 1) {
    if (threadIdx.x < off)
      for (int j = 0; j < 4; ++j) b[threadIdx.x][j] += b[threadIdx.x + off][j];
    __syncthreads();
  }
  if (threadIdx.x == 0)
    for (int j = 0; j < 4; ++j) atomicAdd(&s4[j], b[0][j]);
}

__global__ void k_final(const float* __restrict__ val, const float* __restrict__ s4,
                        const float* __restrict__ g2, const float* __restrict__ be2,
                        float* __restrict__ out) {
  int n = blockIdx.x * 256 + threadIdx.x;
  if (n >= N_NODES) return;
  float mu0 = s4[0] * (1.f / N_NODES), var0 = s4[1] * (1.f / N_NODES) - mu0 * mu0;
  float mu1 = s4[2] * (1.f / N_NODES), var1 = s4[3] * (1.f / N_NODES) - mu1 * mu1;
  float y0 = (val[n * 2] - mu0) * rsqrtf(var0 + BN_EPS) * g2[0] + be2[0];
  float y1 = (val[n * 2 + 1] - mu1) * rsqrtf(var1 + BN_EPS) * g2[1] + be2[1];
  float m = fmaxf(y0, y1);
  float lse = m + __logf(__expf(y0 - m) + __expf(y1 - m));
  out[n * 2] = y0 - lse;
  out[n * 2 + 1] = y1 - lse;
}

// ---------------- launch ----------------
extern "C" void kernel_launch(void* const* d_in, const int* in_sizes, int n_in,
                              void* d_out, int out_size, void* d_ws, size_t ws_size,
                              hipStream_t stream) {
  (void)in_sizes; (void)n_in; (void)out_size; (void)ws_size;
  const float* x        = (const float*)d_in[0];
  const int*   eidx     = (const int*)d_in[1];
  const int*   row      = eidx;
  const int*   col      = eidx + N_EDGES;
  const int*   attr     = (const int*)d_in[2];
  const int*   tim      = (const int*)d_in[3];
  const int*   dire     = (const int*)d_in[4];
  const float* emb_type = (const float*)d_in[5];
  const float* emb_dir  = (const float*)d_in[6];
  const float* w_t      = (const float*)d_in[7];
  const float* b_t      = (const float*)d_in[8];
  const float* Wm[3] = {(const float*)d_in[9],  (const float*)d_in[15], (const float*)d_in[21]};
  const float* bm[3] = {(const float*)d_in[10], (const float*)d_in[16], (const float*)d_in[22]};
  const float* Wr[3] = {(const float*)d_in[11], (const float*)d_in[17], (const float*)d_in[23]};
  const float* br[3] = {(const float*)d_in[12], (const float*)d_in[18], (const float*)d_in[24]};
  const float* g[3]  = {(const float*)d_in[13], (const float*)d_in[19], (const float*)d_in[25]};
  const float* be[3] = {(const float*)d_in[14], (const float*)d_in[20], (const float*)d_in[26]};
  float* out = (float*)d_out;

  // workspace layout
  char* p = (char*)d_ws;
  u32* A     = (u32*)p;   p += sizeof(u32) * (size_t)N_NODES * GK;
  float* gout = (float*)p; p += sizeof(float) * (size_t)N_NODES * DH;
  u32* WT2[2];
  WT2[0] = (u32*)p; p += sizeof(u32) * DH * GK;
  WT2[1] = (u32*)p; p += sizeof(u32) * DH * GK;
  float* bv[2];
  bv[0] = (float*)p; p += sizeof(float) * DH;
  bv[1] = (float*)p; p += sizeof(float) * DH;
  float* val  = (float*)p;  p += sizeof(float) * (size_t)N_NODES * 2;
  float* pmb  = (float*)p;  p += sizeof(float) * (size_t)N_NODES * 2;
  float* stats = (float*)p; p += sizeof(float) * 520;
  float* tlog_s = (float*)p; p += sizeof(float) * N_EDGES;
  int* counts  = (int*)p;   p += sizeof(int) * N_NODES;
  int* cursor  = (int*)p;   p += sizeof(int) * N_NODES;
  int* row_ptr = (int*)p;   p += sizeof(int) * (N_NODES + 1);
  int* col_s   = (int*)p;   p += sizeof(int) * N_EDGES;
  int* ad_s    = (int*)p;   p += sizeof(int) * N_EDGES;
  int* incl    = (int*)p;   p += sizeof(int) * N_NODES;
  int* bsum    = (int*)p;   p += sizeof(int) * SCAN_NB;
  int* boff    = (int*)p;   p += sizeof(int) * SCAN_NB;

  const int EB = (N_EDGES + 255) / 256;      // 3125
  const int NB = (N_NODES + 255) / 256;      // 196
  const int AB = (N_NODES + 3) / 4;          // 12500
  const int GB = (N_NODES + 63) / 64;        // 782
  const int XB = (N_NODES * DH + 255) / 256; // 25000
  const int WB = (DH * GK + 255) / 256;      // 192

  hipMemsetAsync(counts, 0, sizeof(int) * N_NODES, stream);
  hipMemsetAsync(stats, 0, sizeof(float) * 520, stream);

  // CSR
  k_count<<<EB, 256, 0, stream>>>(row, counts);
  k_scan_a<<<SCAN_NB, 256, 0, stream>>>(counts, incl, bsum);
  k_scan_b<<<1, 256, 0, stream>>>(bsum, boff, row_ptr);
  k_scan_c<<<SCAN_NB, 256, 0, stream>>>(incl, counts, boff, row_ptr, cursor);
  k_fill<<<EB, 256, 0, stream>>>(row, col, attr, dire, tim, cursor, col_s, ad_s, tlog_s);

  // weight prep
  for (int l = 0; l < 2; ++l) {
    k_wprep<<<WB, 256, 0, stream>>>(Wm[l], Wr[l], WT2[l]);
    k_bias<<<1, 128, 0, stream>>>(bm[l], br[l], bv[l]);
  }

  // x -> A h-region; edge features -> A e-region (+pad)
  k_conv_x<<<XB, 256, 0, stream>>>(x, A);
  k_aggE<<<N_NODES, 128, 0, stream>>>(row_ptr, ad_s, tlog_s,
                                      emb_type, emb_dir, w_t, b_t, A);

  // layer 0
  k_aggH<<<AB, 256, 0, stream>>>(row_ptr, col_s, A);
  k_mfma<<<GB, 256, 0, stream>>>(A, WT2[0], bv[0], gout);
  k_bnstats<<<256, 256, 0, stream>>>(gout, stats);
  k_bnapply<<<XB, 256, 0, stream>>>(gout, stats, g[0], be[0], A);

  // layer 1
  k_aggH<<<AB, 256, 0, stream>>>(row_ptr, col_s, A);
  k_mfma<<<GB, 256, 0, stream>>>(A, WT2[1], bv[1], gout);
  k_bnstats<<<256, 256, 0, stream>>>(gout, stats + 256);
  k_bnapply<<<XB, 256, 0, stream>>>(gout, stats + 256, g[1], be[1], A);

  // layer 2
  k_l2_dense<<<AB, 256, 0, stream>>>(A, Wm[2], bm[2], Wr[2], br[2], val, pmb);
  k_agg2<<<NB, 256, 0, stream>>>(row_ptr, col_s, pmb, val);
  k_bnstats2<<<64, 256, 0, stream>>>(val, stats + 512);
  k_final<<<NB, 256, 0, stream>>>(val, stats + 512, g[2], be[2], out);
}

// Round 5
// 418.926 us; speedup vs baseline: 2.3045x; 1.2587x over previous
//
#include <hip/hip_runtime.h>
#include <math.h>

#define N_NODES 50000
#define N_EDGES 800000
#define DIN 128
#define DH 128
#define EA_C 50
#define DE 100
#define FM 228      // DIN + DE
#define AS 320      // A stride in u32: 128 aggH(hi/lo) + 64 h(bf16 pairs) + 100 e(hi/lo) + 28 pad
#define WKL 384     // logical K (W stride): 128 + 128 + 100 + 28
#define BN_EPS 1e-5f
#define SCAN_NB ((N_NODES + 255) / 256)   // 196

typedef __attribute__((ext_vector_type(8))) short short8;
typedef __attribute__((ext_vector_type(4))) float f32x4;
typedef unsigned int u32;
typedef unsigned short u16;

// ---- bf16 hi/lo packing: u32 = hi | (lo << 16); value = bf2f(hi)+bf2f(lo) ----
__device__ inline u16 f2bf(float f) {
  u32 u = __float_as_uint(f);
  u32 r = (u + 0x7fffu + ((u >> 16) & 1u)) >> 16;
  return (u16)r;
}
__device__ inline float bf2f(u16 h) { return __uint_as_float(((u32)h) << 16); }
__device__ inline u32 pack_hl(float v) {
  u16 hi = f2bf(v);
  u16 lo = f2bf(v - bf2f(hi));
  return (u32)hi | ((u32)lo << 16);
}
__device__ inline float unpack_hl(u32 p) {
  return bf2f((u16)(p & 0xffffu)) + bf2f((u16)(p >> 16));
}

// ---------------- CSR build ----------------
__global__ void k_count(const int* __restrict__ row, int* __restrict__ counts) {
  int e = blockIdx.x * 256 + threadIdx.x;
  if (e < N_EDGES) atomicAdd(&counts[row[e]], 1);
}

__global__ void k_scan_a(const int* __restrict__ counts, int* __restrict__ incl,
                         int* __restrict__ bsum) {
  __shared__ int buf[256];
  int i = blockIdx.x * 256 + threadIdx.x;
  int v = (i < N_NODES) ? counts[i] : 0;
  buf[threadIdx.x] = v;
  __syncthreads();
#pragma unroll
  for (int off = 1; off < 256; off <<= 1) {
    int t = (threadIdx.x >= off) ? buf[threadIdx.x - off] : 0;
    __syncthreads();
    buf[threadIdx.x] += t;
    __syncthreads();
  }
  if (i < N_NODES) incl[i] = buf[threadIdx.x];
  if (threadIdx.x == 255) bsum[blockIdx.x] = buf[255];
}

__global__ void k_scan_b(const int* __restrict__ bsum, int* __restrict__ boff,
                         int* __restrict__ row_ptr) {
  __shared__ int buf[256];
  int v = (threadIdx.x < SCAN_NB) ? bsum[threadIdx.x] : 0;
  buf[threadIdx.x] = v;
  __syncthreads();
#pragma unroll
  for (int off = 1; off < 256; off <<= 1) {
    int t = (threadIdx.x >= off) ? buf[threadIdx.x - off] : 0;
    __syncthreads();
    buf[threadIdx.x] += t;
    __syncthreads();
  }
  if (threadIdx.x < SCAN_NB) boff[threadIdx.x] = buf[threadIdx.x] - v;
  if (threadIdx.x == 255) row_ptr[N_NODES] = buf[255];
}

__global__ void k_scan_c(const int* __restrict__ incl, const int* __restrict__ counts,
                         const int* __restrict__ boff, int* __restrict__ row_ptr,
                         int* __restrict__ cursor) {
  int i = blockIdx.x * 256 + threadIdx.x;
  if (i < N_NODES) {
    int p = incl[i] - counts[i] + boff[blockIdx.x];
    row_ptr[i] = p;
    cursor[i] = p;
  }
}

__global__ void k_fill(const int* __restrict__ row, const int* __restrict__ col,
                       const int* __restrict__ attr, const int* __restrict__ dire,
                       const int* __restrict__ tim,
                       int* __restrict__ cursor, int* __restrict__ col_s,
                       int* __restrict__ ad_s, float* __restrict__ tlog_s) {
  int e = blockIdx.x * 256 + threadIdx.x;
  if (e < N_EDGES) {
    int r = row[e];
    int slot = atomicAdd(&cursor[r], 1);
    col_s[slot] = col[e];
    ad_s[slot] = attr[e] | (dire[e] << 16);
    tlog_s[slot] = __logf((float)tim[e] + 1.0f);
  }
}

// ---------------- x -> A h16 plane (bf16) ----------------
__global__ void k_conv_x(const float* __restrict__ x, u32* __restrict__ A) {
  int idx = blockIdx.x * 256 + threadIdx.x;
  if (idx >= N_NODES * DH) return;
  int n = idx >> 7, c = idx & 127;
  ((u16*)(A + (size_t)n * AS + 128))[c] = f2bf(x[idx]);
}

// ---------------- edge-embedding aggregation -> A cols 192..291 (+pad) -------
__global__ void k_aggE(const int* __restrict__ row_ptr, const int* __restrict__ ad_s,
                       const float* __restrict__ tlog_s,
                       const float* __restrict__ emb_type, const float* __restrict__ emb_dir,
                       const float* __restrict__ w_t, const float* __restrict__ b_t,
                       u32* __restrict__ A) {
  int n = blockIdx.x;
  int wave = threadIdx.x >> 6;
  int lane = threadIdx.x & 63;
  if (lane >= EA_C) {
    // zero pad cols 292..319 (28 cols over 2 waves x 14 lanes)
    int col = (wave == 0) ? (292 + lane - EA_C) : (306 + lane - EA_C);
    A[(size_t)n * AS + col] = 0u;
    return;
  }
  int s = row_ptr[n], epos = row_ptr[n + 1];
  float acc = 0.f;
  if (wave == 0) {
    for (int p = s; p < epos; ++p) {
      int ad = ad_s[p];
      acc += emb_type[(ad & 0xffff) * EA_C + lane] + emb_dir[(ad >> 16) * EA_C + lane];
    }
    A[(size_t)n * AS + 192 + lane] = pack_hl(acc);
  } else {
    float w = w_t[lane], b = b_t[lane];
    for (int p = s; p < epos; ++p) {
      acc += __cosf(tlog_s[p] * w + b);
    }
    A[(size_t)n * AS + 242 + lane] = pack_hl(acc);
  }
}

// ---------------- neighbor aggregation: h16 plane -> A cols 0..127 (hi/lo) ---
__global__ void k_aggH(const int* __restrict__ row_ptr, const int* __restrict__ col_s,
                       u32* __restrict__ A) {
  int wave = threadIdx.x >> 6, lane = threadIdx.x & 63;
  int n = blockIdx.x * 4 + wave;
  if (n >= N_NODES) return;
  int s = row_ptr[n], epos = row_ptr[n + 1];
  float ax = 0.f, ay = 0.f;
  int p = s;
  for (; p + 3 < epos; p += 4) {
    int c0 = col_s[p], c1 = col_s[p + 1], c2 = col_s[p + 2], c3 = col_s[p + 3];
    u32 v0 = A[(size_t)c0 * AS + 128 + lane];
    u32 v1 = A[(size_t)c1 * AS + 128 + lane];
    u32 v2 = A[(size_t)c2 * AS + 128 + lane];
    u32 v3 = A[(size_t)c3 * AS + 128 + lane];
    ax += bf2f((u16)(v0 & 0xffffu)) + bf2f((u16)(v1 & 0xffffu)) +
          bf2f((u16)(v2 & 0xffffu)) + bf2f((u16)(v3 & 0xffffu));
    ay += bf2f((u16)(v0 >> 16)) + bf2f((u16)(v1 >> 16)) +
          bf2f((u16)(v2 >> 16)) + bf2f((u16)(v3 >> 16));
  }
  for (; p < epos; ++p) {
    u32 v = A[(size_t)col_s[p] * AS + 128 + lane];
    ax += bf2f((u16)(v & 0xffffu));
    ay += bf2f((u16)(v >> 16));
  }
  uint2 o; o.x = pack_hl(ax); o.y = pack_hl(ay);
  *reinterpret_cast<uint2*>(A + (size_t)n * AS + 2 * lane) = o;
}

// ---------------- weight prep: WT2[col][logical k 0..383] packed hi/lo -------
__global__ void k_wprep(const float* __restrict__ Wm, const float* __restrict__ Wr,
                        u32* __restrict__ WT2) {
  int idx = blockIdx.x * 256 + threadIdx.x;
  if (idx >= DH * WKL) return;
  int o = idx / WKL, k = idx - o * WKL;
  float v;
  if (k < 128) v = 0.5f * Wm[o * FM + k];
  else if (k < 256) v = Wr[o * DIN + (k - 128)];
  else if (k < 356) v = 0.5f * Wm[o * FM + (k - 128)];
  else v = 0.f;
  WT2[idx] = pack_hl(v);
}

__global__ void k_bias(const float* __restrict__ bm, const float* __restrict__ br,
                       float* __restrict__ bv) {
  int o = threadIdx.x;
  if (o < DH) bv[o] = 0.5f * bm[o] + br[o];
}

// ---------------- MFMA GEMM, 3-phase K ----------------
// logical K: [0,128) aggH hi/lo @ A cols kl; [128,256) h bf16 @ A u16 256+(kl-128);
// [256,384) e hi/lo+pad @ A cols kl-64. W: [col][384] hi/lo.
__global__ __launch_bounds__(256) void k_mfma(const u32* __restrict__ A,
                                              const u32* __restrict__ W,
                                              const float* __restrict__ bv,
                                              float* __restrict__ out) {
  __shared__ u16 Ah[64][32], Al[64][32];
  __shared__ u16 Wh[128][32], Wl[128][32];
  int tid = threadIdx.x;
  int wv = tid >> 6, ln = tid & 63;
  int node0 = blockIdx.x * 64;

  f32x4 acc[8];
#pragma unroll
  for (int nt = 0; nt < 8; ++nt) acc[nt] = (f32x4){0.f, 0.f, 0.f, 0.f};

  int ar = tid >> 2, aq = tid & 3;
  int wc = tid >> 1, wk = (tid & 1) * 16;
  int an = node0 + ar;
  bool valid = an < N_NODES;
  const u32* aptr = A + (size_t)an * AS;
  const u32* wptr = W + (size_t)wc * WKL + wk;

  const u16* afh = &Ah[(wv << 4) + (ln & 15)][(ln >> 4) * 8];
  const u16* afl = &Al[(wv << 4) + (ln & 15)][(ln >> 4) * 8];

#pragma unroll
  for (int ch = 0; ch < 12; ++ch) {
    const int kl = ch * 32;
    const bool ph2 = (ch >= 4 && ch < 8);
    uint4 a0 = make_uint4(0, 0, 0, 0), a1 = make_uint4(0, 0, 0, 0);
    if (!ph2) {
      int acol = (ch < 4 ? kl : kl - 64) + aq * 8;
      if (valid) {
        a0 = *reinterpret_cast<const uint4*>(aptr + acol);
        a1 = *reinterpret_cast<const uint4*>(aptr + acol + 4);
      }
    } else {
      int acol = 128 + ((kl - 128) >> 1) + aq * 4;
      if (valid) a0 = *reinterpret_cast<const uint4*>(aptr + acol);
    }
    uint4 w0 = *reinterpret_cast<const uint4*>(wptr + kl);
    uint4 w1 = *reinterpret_cast<const uint4*>(wptr + kl + 4);
    uint4 w2 = *reinterpret_cast<const uint4*>(wptr + kl + 8);
    uint4 w3 = *reinterpret_cast<const uint4*>(wptr + kl + 12);

    __syncthreads();   // protect previous iteration's frag reads

    if (!ph2) {
      u32 va[8] = {a0.x, a0.y, a0.z, a0.w, a1.x, a1.y, a1.z, a1.w};
      short8 h, l;
#pragma unroll
      for (int j = 0; j < 8; ++j) { h[j] = (short)(va[j] & 0xffffu); l[j] = (short)(va[j] >> 16); }
      *reinterpret_cast<short8*>(&Ah[ar][aq * 8]) = h;
      *reinterpret_cast<short8*>(&Al[ar][aq * 8]) = l;
    } else {
      *reinterpret_cast<short8*>(&Ah[ar][aq * 8]) = *reinterpret_cast<const short8*>(&a0);
    }
    {
      u32 vw[16] = {w0.x, w0.y, w0.z, w0.w, w1.x, w1.y, w1.z, w1.w,
                    w2.x, w2.y, w2.z, w2.w, w3.x, w3.y, w3.z, w3.w};
      short8 h0, l0, h1, l1;
#pragma unroll
      for (int j = 0; j < 8; ++j) {
        h0[j] = (short)(vw[j] & 0xffffu);     l0[j] = (short)(vw[j] >> 16);
        h1[j] = (short)(vw[j + 8] & 0xffffu); l1[j] = (short)(vw[j + 8] >> 16);
      }
      *reinterpret_cast<short8*>(&Wh[wc][wk]) = h0;
      *reinterpret_cast<short8*>(&Wh[wc][wk + 8]) = h1;
      *reinterpret_cast<short8*>(&Wl[wc][wk]) = l0;
      *reinterpret_cast<short8*>(&Wl[wc][wk + 8]) = l1;
    }

    __syncthreads();   // LDS writes visible

    short8 ah = *reinterpret_cast<const short8*>(afh);
    short8 al = *reinterpret_cast<const short8*>(afl);
#pragma unroll
    for (int nt = 0; nt < 8; ++nt) {
      short8 bh = *reinterpret_cast<const short8*>(&Wh[nt * 16 + (ln & 15)][(ln >> 4) * 8]);
      short8 bl = *reinterpret_cast<const short8*>(&Wl[nt * 16 + (ln & 15)][(ln >> 4) * 8]);
      acc[nt] = __builtin_amdgcn_mfma_f32_16x16x32_bf16(ah, bh, acc[nt], 0, 0, 0);
      if (!ph2) acc[nt] = __builtin_amdgcn_mfma_f32_16x16x32_bf16(al, bh, acc[nt], 0, 0, 0);
      acc[nt] = __builtin_amdgcn_mfma_f32_16x16x32_bf16(ah, bl, acc[nt], 0, 0, 0);
    }
  }

  int rbase = node0 + (wv << 4) + ((ln >> 4) << 2);
  int colb = ln & 15;
#pragma unroll
  for (int nt = 0; nt < 8; ++nt) {
    int col = nt * 16 + colb;
    float bb = bv[col];
#pragma unroll
    for (int r = 0; r < 4; ++r) {
      int n = rbase + r;
      if (n < N_NODES) out[(size_t)n * DH + col] = acc[nt][r] + bb;
    }
  }
}

// ---------------- BatchNorm stats ----------------
__global__ void k_bnstats(const float* __restrict__ x, float* __restrict__ stats) {
  int c = threadIdx.x & 127;
  int half = threadIdx.x >> 7;
  float s = 0.f, q = 0.f;
  for (int r = blockIdx.x * 2 + half; r < N_NODES; r += gridDim.x * 2) {
    float v = x[(size_t)r * DH + c];
    s += v; q += v * v;
  }
  __shared__ float ls[256], lq[256];
  ls[threadIdx.x] = s; lq[threadIdx.x] = q;
  __syncthreads();
  if (half == 0) {
    s += ls[128 + c]; q += lq[128 + c];
    atomicAdd(&stats[c], s);
    atomicAdd(&stats[128 + c], q);
  }
}

// BN + ELU -> h16 plane (bf16)
__global__ void k_bnapply(const float* __restrict__ x, const float* __restrict__ stats,
                          const float* __restrict__ g, const float* __restrict__ be,
                          u32* __restrict__ A) {
  int idx = blockIdx.x * 256 + threadIdx.x;
  if (idx >= N_NODES * DH) return;
  int n = idx >> 7, c = idx & 127;
  float mu = stats[c] * (1.0f / N_NODES);
  float var = stats[128 + c] * (1.0f / N_NODES) - mu * mu;
  float y = (x[idx] - mu) * rsqrtf(var + BN_EPS) * g[c] + be[c];
  y = y > 0.f ? y : expm1f(y);
  ((u16*)(A + (size_t)n * AS + 128))[c] = f2bf(y);
}

// ---------------- layer 2 (project-first, dout=2) ----------------
__global__ void k_l2_dense(const u32* __restrict__ A,
                           const float* __restrict__ Wm2, const float* __restrict__ bm2,
                           const float* __restrict__ Wr2, const float* __restrict__ br2,
                           float* __restrict__ val, float* __restrict__ pm) {
  int wave = threadIdx.x >> 6, lane = threadIdx.x & 63;
  int n = blockIdx.x * 4 + wave;
  if (n >= N_NODES) return;
  const u32* ar = A + (size_t)n * AS;
  const u16* h16 = (const u16*)(ar + 128);
  float h0 = bf2f(h16[lane]);
  float h1 = bf2f(h16[lane + 64]);
  float e0 = unpack_hl(ar[192 + lane]);
  float e1 = (lane < DE - 64) ? unpack_hl(ar[256 + lane]) : 0.f;

  float pm0 = h0 * Wm2[lane] + h1 * Wm2[lane + 64];
  float pm1 = h0 * Wm2[FM + lane] + h1 * Wm2[FM + lane + 64];
  float ve0 = e0 * Wm2[DIN + lane] + ((lane < DE - 64) ? e1 * Wm2[DIN + lane + 64] : 0.f);
  float ve1 = e0 * Wm2[FM + DIN + lane] + ((lane < DE - 64) ? e1 * Wm2[FM + DIN + lane + 64] : 0.f);
  float pr0 = h0 * Wr2[lane] + h1 * Wr2[lane + 64];
  float pr1 = h0 * Wr2[DH + lane] + h1 * Wr2[DH + lane + 64];

#pragma unroll
  for (int m = 32; m >= 1; m >>= 1) {
    pm0 += __shfl_xor(pm0, m, 64); pm1 += __shfl_xor(pm1, m, 64);
    ve0 += __shfl_xor(ve0, m, 64); ve1 += __shfl_xor(ve1, m, 64);
    pr0 += __shfl_xor(pr0, m, 64); pr1 += __shfl_xor(pr1, m, 64);
  }
  if (lane == 0) {
    val[n * 2 + 0] = 0.5f * (ve0 + bm2[0]) + pr0 + br2[0];
    val[n * 2 + 1] = 0.5f * (ve1 + bm2[1]) + pr1 + br2[1];
    pm[n * 2 + 0] = pm0;
    pm[n * 2 + 1] = pm1;
  }
}

__global__ void k_agg2(const int* __restrict__ row_ptr, const int* __restrict__ col_s,
                       const float* __restrict__ pm, float* __restrict__ val) {
  int n = blockIdx.x * 256 + threadIdx.x;
  if (n >= N_NODES) return;
  float a0 = 0.f, a1 = 0.f;
  int s = row_ptr[n], e = row_ptr[n + 1];
  for (int p = s; p < e; ++p) {
    int c = col_s[p];
    a0 += pm[c * 2]; a1 += pm[c * 2 + 1];
  }
  val[n * 2] += 0.5f * a0;
  val[n * 2 + 1] += 0.5f * a1;
}

__global__ void k_bnstats2(const float* __restrict__ val, float* __restrict__ s4) {
  float s0 = 0.f, q0 = 0.f, s1 = 0.f, q1 = 0.f;
  for (int n = blockIdx.x * 256 + threadIdx.x; n < N_NODES; n += gridDim.x * 256) {
    float v0 = val[n * 2], v1 = val[n * 2 + 1];
    s0 += v0; q0 += v0 * v0; s1 += v1; q1 += v1 * v1;
  }
  __shared__ float b[256][4];
  b[threadIdx.x][0] = s0; b[threadIdx.x][1] = q0;
  b[threadIdx.x][2] = s1; b[threadIdx.x][3] = q1;
  __syncthreads();
  for (int off = 128; off >= 1; off >>= 1) {
    if (threadIdx.x < off)
      for (int j = 0; j < 4; ++j) b[threadIdx.x][j] += b[threadIdx.x + off][j];
    __syncthreads();
  }
  if (threadIdx.x == 0)
    for (int j = 0; j < 4; ++j) atomicAdd(&s4[j], b[0][j]);
}

__global__ void k_final(const float* __restrict__ val, const float* __restrict__ s4,
                        const float* __restrict__ g2, const float* __restrict__ be2,
                        float* __restrict__ out) {
  int n = blockIdx.x * 256 + threadIdx.x;
  if (n >= N_NODES) return;
  float mu0 = s4[0] * (1.f / N_NODES), var0 = s4[1] * (1.f / N_NODES) - mu0 * mu0;
  float mu1 = s4[2] * (1.f / N_NODES), var1 = s4[3] * (1.f / N_NODES) - mu1 * mu1;
  float y0 = (val[n * 2] - mu0) * rsqrtf(var0 + BN_EPS) * g2[0] + be2[0];
  float y1 = (val[n * 2 + 1] - mu1) * rsqrtf(var1 + BN_EPS) * g2[1] + be2[1];
  float m = fmaxf(y0, y1);
  float lse = m + __logf(__expf(y0 - m) + __expf(y1 - m));
  out[n * 2] = y0 - lse;
  out[n * 2 + 1] = y1 - lse;
}

// ---------------- launch ----------------
extern "C" void kernel_launch(void* const* d_in, const int* in_sizes, int n_in,
                              void* d_out, int out_size, void* d_ws, size_t ws_size,
                              hipStream_t stream) {
  (void)in_sizes; (void)n_in; (void)out_size; (void)ws_size;
  const float* x        = (const float*)d_in[0];
  const int*   eidx     = (const int*)d_in[1];
  const int*   row      = eidx;
  const int*   col      = eidx + N_EDGES;
  const int*   attr     = (const int*)d_in[2];
  const int*   tim      = (const int*)d_in[3];
  const int*   dire     = (const int*)d_in[4];
  const float* emb_type = (const float*)d_in[5];
  const float* emb_dir  = (const float*)d_in[6];
  const float* w_t      = (const float*)d_in[7];
  const float* b_t      = (const float*)d_in[8];
  const float* Wm[3] = {(const float*)d_in[9],  (const float*)d_in[15], (const float*)d_in[21]};
  const float* bm[3] = {(const float*)d_in[10], (const float*)d_in[16], (const float*)d_in[22]};
  const float* Wr[3] = {(const float*)d_in[11], (const float*)d_in[17], (const float*)d_in[23]};
  const float* br[3] = {(const float*)d_in[12], (const float*)d_in[18], (const float*)d_in[24]};
  const float* g[3]  = {(const float*)d_in[13], (const float*)d_in[19], (const float*)d_in[25]};
  const float* be[3] = {(const float*)d_in[14], (const float*)d_in[20], (const float*)d_in[26]};
  float* out = (float*)d_out;

  // workspace layout (~101 MB)
  char* p = (char*)d_ws;
  u32* A     = (u32*)p;   p += sizeof(u32) * (size_t)N_NODES * AS;    // 64 MB
  float* gout = (float*)p; p += sizeof(float) * (size_t)N_NODES * DH; // 25.6 MB
  u32* WT2[2];
  WT2[0] = (u32*)p; p += sizeof(u32) * DH * WKL;
  WT2[1] = (u32*)p; p += sizeof(u32) * DH * WKL;
  float* bv[2];
  bv[0] = (float*)p; p += sizeof(float) * DH;
  bv[1] = (float*)p; p += sizeof(float) * DH;
  float* val  = (float*)p;  p += sizeof(float) * (size_t)N_NODES * 2;
  float* pmb  = (float*)p;  p += sizeof(float) * (size_t)N_NODES * 2;
  float* stats = (float*)p; p += sizeof(float) * 520;
  float* tlog_s = (float*)p; p += sizeof(float) * N_EDGES;
  int* counts  = (int*)p;   p += sizeof(int) * N_NODES;
  int* cursor  = (int*)p;   p += sizeof(int) * N_NODES;
  int* row_ptr = (int*)p;   p += sizeof(int) * (N_NODES + 1);
  int* col_s   = (int*)p;   p += sizeof(int) * N_EDGES;
  int* ad_s    = (int*)p;   p += sizeof(int) * N_EDGES;
  int* incl    = (int*)p;   p += sizeof(int) * N_NODES;
  int* bsum    = (int*)p;   p += sizeof(int) * SCAN_NB;
  int* boff    = (int*)p;   p += sizeof(int) * SCAN_NB;

  const int EB = (N_EDGES + 255) / 256;      // 3125
  const int NB = (N_NODES + 255) / 256;      // 196
  const int AB = (N_NODES + 3) / 4;          // 12500
  const int GB = (N_NODES + 63) / 64;        // 782
  const int XB = (N_NODES * DH + 255) / 256; // 25000
  const int WB = (DH * WKL + 255) / 256;     // 192

  hipMemsetAsync(counts, 0, sizeof(int) * N_NODES, stream);
  hipMemsetAsync(stats, 0, sizeof(float) * 520, stream);

  // CSR
  k_count<<<EB, 256, 0, stream>>>(row, counts);
  k_scan_a<<<SCAN_NB, 256, 0, stream>>>(counts, incl, bsum);
  k_scan_b<<<1, 256, 0, stream>>>(bsum, boff, row_ptr);
  k_scan_c<<<SCAN_NB, 256, 0, stream>>>(incl, counts, boff, row_ptr, cursor);
  k_fill<<<EB, 256, 0, stream>>>(row, col, attr, dire, tim, cursor, col_s, ad_s, tlog_s);

  // weight prep
  for (int l = 0; l < 2; ++l) {
    k_wprep<<<WB, 256, 0, stream>>>(Wm[l], Wr[l], WT2[l]);
    k_bias<<<1, 128, 0, stream>>>(bm[l], br[l], bv[l]);
  }

  // x -> h16 plane; edge features -> e region (+pad)
  k_conv_x<<<XB, 256, 0, stream>>>(x, A);
  k_aggE<<<N_NODES, 128, 0, stream>>>(row_ptr, ad_s, tlog_s,
                                      emb_type, emb_dir, w_t, b_t, A);

  // layer 0
  k_aggH<<<AB, 256, 0, stream>>>(row_ptr, col_s, A);
  k_mfma<<<GB, 256, 0, stream>>>(A, WT2[0], bv[0], gout);
  k_bnstats<<<256, 256, 0, stream>>>(gout, stats);
  k_bnapply<<<XB, 256, 0, stream>>>(gout, stats, g[0], be[0], A);

  // layer 1
  k_aggH<<<AB, 256, 0, stream>>>(row_ptr, col_s, A);
  k_mfma<<<GB, 256, 0, stream>>>(A, WT2[1], bv[1], gout);
  k_bnstats<<<256, 256, 0, stream>>>(gout, stats + 256);
  k_bnapply<<<XB, 256, 0, stream>>>(gout, stats + 256, g[1], be[1], A);

  // layer 2
  k_l2_dense<<<AB, 256, 0, stream>>>(A, Wm[2], bm[2], Wr[2], br[2], val, pmb);
  k_agg2<<<NB, 256, 0, stream>>>(row_ptr, col_s, pmb, val);
  k_bnstats2<<<64, 256, 0, stream>>>(val, stats + 512);
  k_final<<<NB, 256, 0, stream>>>(val, stats + 512, g[2], be[2], out);
}

// Round 6
// 412.451 us; speedup vs baseline: 2.3406x; 1.0157x over previous
//
#include <hip/hip_runtime.h>
#include <math.h>

#define N_NODES 50000
#define N_EDGES 800000
#define DIN 128
#define DH 128
#define EA_C 50
#define DE 100
#define FM 228      // DIN + DE
#define AS 320      // A stride in u32: 128 aggH(hi/lo) + 64 h(bf16 pairs) + 100 e(hi/lo) + 28 pad
#define WKL 384     // logical K (W stride): 128 + 128 + 100 + 28
#define BN_EPS 1e-5f
#define SCAN_NB ((N_NODES + 255) / 256)   // 196

typedef __attribute__((ext_vector_type(8))) short short8;
typedef __attribute__((ext_vector_type(4))) float f32x4;
typedef unsigned int u32;
typedef unsigned short u16;

// ---- bf16 hi/lo packing ----
__device__ inline u16 f2bf(float f) {
  u32 u = __float_as_uint(f);
  u32 r = (u + 0x7fffu + ((u >> 16) & 1u)) >> 16;
  return (u16)r;
}
__device__ inline float bf2f(u16 h) { return __uint_as_float(((u32)h) << 16); }
__device__ inline u32 pack_hl(float v) {
  u16 hi = f2bf(v);
  u16 lo = f2bf(v - bf2f(hi));
  return (u32)hi | ((u32)lo << 16);
}
__device__ inline float unpack_hl(u32 p) {
  return bf2f((u16)(p & 0xffffu)) + bf2f((u16)(p >> 16));
}

// ---------------- CSR build ----------------
__global__ void k_count(const int* __restrict__ row, int* __restrict__ counts) {
  int e = blockIdx.x * 256 + threadIdx.x;
  if (e < N_EDGES) atomicAdd(&counts[row[e]], 1);
}

__global__ void k_scan_a(const int* __restrict__ counts, int* __restrict__ incl,
                         int* __restrict__ bsum) {
  __shared__ int buf[256];
  int i = blockIdx.x * 256 + threadIdx.x;
  int v = (i < N_NODES) ? counts[i] : 0;
  buf[threadIdx.x] = v;
  __syncthreads();
#pragma unroll
  for (int off = 1; off < 256; off <<= 1) {
    int t = (threadIdx.x >= off) ? buf[threadIdx.x - off] : 0;
    __syncthreads();
    buf[threadIdx.x] += t;
    __syncthreads();
  }
  if (i < N_NODES) incl[i] = buf[threadIdx.x];
  if (threadIdx.x == 255) bsum[blockIdx.x] = buf[255];
}

__global__ void k_scan_b(const int* __restrict__ bsum, int* __restrict__ boff,
                         int* __restrict__ row_ptr) {
  __shared__ int buf[256];
  int v = (threadIdx.x < SCAN_NB) ? bsum[threadIdx.x] : 0;
  buf[threadIdx.x] = v;
  __syncthreads();
#pragma unroll
  for (int off = 1; off < 256; off <<= 1) {
    int t = (threadIdx.x >= off) ? buf[threadIdx.x - off] : 0;
    __syncthreads();
    buf[threadIdx.x] += t;
    __syncthreads();
  }
  if (threadIdx.x < SCAN_NB) boff[threadIdx.x] = buf[threadIdx.x] - v;
  if (threadIdx.x == 255) row_ptr[N_NODES] = buf[255];
}

__global__ void k_scan_c(const int* __restrict__ incl, const int* __restrict__ counts,
                         const int* __restrict__ boff, int* __restrict__ row_ptr,
                         int* __restrict__ cursor) {
  int i = blockIdx.x * 256 + threadIdx.x;
  if (i < N_NODES) {
    int p = incl[i] - counts[i] + boff[blockIdx.x];
    row_ptr[i] = p;
    cursor[i] = p;
  }
}

// fill CSR: ONE 8B record per edge: x = col | attr<<16 | dir<<20, y = log(t+1)
__global__ void k_fill(const int* __restrict__ row, const int* __restrict__ col,
                       const int* __restrict__ attr, const int* __restrict__ dire,
                       const int* __restrict__ tim,
                       int* __restrict__ cursor, uint2* __restrict__ er_s) {
  int e = blockIdx.x * 256 + threadIdx.x;
  if (e < N_EDGES) {
    int r = row[e];
    int slot = atomicAdd(&cursor[r], 1);
    uint2 rec;
    rec.x = (u32)col[e] | ((u32)attr[e] << 16) | ((u32)dire[e] << 20);
    rec.y = __float_as_uint(__logf((float)tim[e] + 1.0f));
    er_s[slot] = rec;
  }
}

// ---------------- x -> A h16 plane (bf16) ----------------
__global__ void k_conv_x(const float* __restrict__ x, u32* __restrict__ A) {
  int idx = blockIdx.x * 256 + threadIdx.x;
  if (idx >= N_NODES * DH) return;
  int n = idx >> 7, c = idx & 127;
  ((u16*)(A + (size_t)n * AS + 128))[c] = f2bf(x[idx]);
}

// ---------------- edge-embedding aggregation -> A cols 192..291 (+pad) -------
__global__ void k_aggE(const int* __restrict__ row_ptr, const uint2* __restrict__ er_s,
                       const float* __restrict__ emb_type, const float* __restrict__ emb_dir,
                       const float* __restrict__ w_t, const float* __restrict__ b_t,
                       u32* __restrict__ A) {
  int n = blockIdx.x;
  int wave = threadIdx.x >> 6;
  int lane = threadIdx.x & 63;
  if (lane >= EA_C) {
    int col = (wave == 0) ? (292 + lane - EA_C) : (306 + lane - EA_C);
    A[(size_t)n * AS + col] = 0u;
    return;
  }
  int s = row_ptr[n], epos = row_ptr[n + 1];
  float acc = 0.f;
  if (wave == 0) {
    for (int p = s; p < epos; ++p) {
      u32 adc = er_s[p].x;
      acc += emb_type[((adc >> 16) & 0xF) * EA_C + lane] + emb_dir[(adc >> 20) * EA_C + lane];
    }
    A[(size_t)n * AS + 192 + lane] = pack_hl(acc);
  } else {
    float w = w_t[lane], b = b_t[lane];
    for (int p = s; p < epos; ++p) {
      acc += __cosf(__uint_as_float(er_s[p].y) * w + b);
    }
    A[(size_t)n * AS + 242 + lane] = pack_hl(acc);
  }
}

// ---------------- neighbor aggregation: h16 plane -> A cols 0..127 (hi/lo) ---
__global__ void k_aggH(const int* __restrict__ row_ptr, const uint2* __restrict__ er_s,
                       u32* __restrict__ A) {
  int wave = threadIdx.x >> 6, lane = threadIdx.x & 63;
  int n = blockIdx.x * 4 + wave;
  if (n >= N_NODES) return;
  int s = row_ptr[n], epos = row_ptr[n + 1];
  float ax = 0.f, ay = 0.f;
  int p = s;
  for (; p + 3 < epos; p += 4) {
    int c0 = er_s[p].x & 0xffff, c1 = er_s[p + 1].x & 0xffff;
    int c2 = er_s[p + 2].x & 0xffff, c3 = er_s[p + 3].x & 0xffff;
    u32 v0 = A[(size_t)c0 * AS + 128 + lane];
    u32 v1 = A[(size_t)c1 * AS + 128 + lane];
    u32 v2 = A[(size_t)c2 * AS + 128 + lane];
    u32 v3 = A[(size_t)c3 * AS + 128 + lane];
    ax += bf2f((u16)(v0 & 0xffffu)) + bf2f((u16)(v1 & 0xffffu)) +
          bf2f((u16)(v2 & 0xffffu)) + bf2f((u16)(v3 & 0xffffu));
    ay += bf2f((u16)(v0 >> 16)) + bf2f((u16)(v1 >> 16)) +
          bf2f((u16)(v2 >> 16)) + bf2f((u16)(v3 >> 16));
  }
  for (; p < epos; ++p) {
    u32 v = A[(size_t)(er_s[p].x & 0xffff) * AS + 128 + lane];
    ax += bf2f((u16)(v & 0xffffu));
    ay += bf2f((u16)(v >> 16));
  }
  uint2 o; o.x = pack_hl(ax); o.y = pack_hl(ay);
  *reinterpret_cast<uint2*>(A + (size_t)n * AS + 2 * lane) = o;
}

// ---------------- weight prep ----------------
__global__ void k_wprep(const float* __restrict__ Wm, const float* __restrict__ Wr,
                        u32* __restrict__ WT2) {
  int idx = blockIdx.x * 256 + threadIdx.x;
  if (idx >= DH * WKL) return;
  int o = idx / WKL, k = idx - o * WKL;
  float v;
  if (k < 128) v = 0.5f * Wm[o * FM + k];
  else if (k < 256) v = Wr[o * DIN + (k - 128)];
  else if (k < 356) v = 0.5f * Wm[o * FM + (k - 128)];
  else v = 0.f;
  WT2[idx] = pack_hl(v);
}

__global__ void k_bias(const float* __restrict__ bm, const float* __restrict__ br,
                       float* __restrict__ bv) {
  int o = threadIdx.x;
  if (o < DH) bv[o] = 0.5f * bm[o] + br[o];
}

// ---------------- MFMA GEMM, 3-phase K, fused BN-stats epilogue ----------------
__global__ __launch_bounds__(256) void k_mfma(const u32* __restrict__ A,
                                              const u32* __restrict__ W,
                                              const float* __restrict__ bv,
                                              float* __restrict__ out,
                                              float* __restrict__ stats) {
  __shared__ u16 Ah[64][32], Al[64][32];
  __shared__ u16 Wh[128][32], Wl[128][32];
  __shared__ float sstat[DH], qstat[DH];
  int tid = threadIdx.x;
  int wv = tid >> 6, ln = tid & 63;
  int node0 = blockIdx.x * 64;

  for (int i = tid; i < DH; i += 256) { sstat[i] = 0.f; qstat[i] = 0.f; }

  f32x4 acc[8];
#pragma unroll
  for (int nt = 0; nt < 8; ++nt) acc[nt] = (f32x4){0.f, 0.f, 0.f, 0.f};

  int ar = tid >> 2, aq = tid & 3;
  int wc = tid >> 1, wk = (tid & 1) * 16;
  int an = node0 + ar;
  bool valid = an < N_NODES;
  const u32* aptr = A + (size_t)an * AS;
  const u32* wptr = W + (size_t)wc * WKL + wk;

  const u16* afh = &Ah[(wv << 4) + (ln & 15)][(ln >> 4) * 8];
  const u16* afl = &Al[(wv << 4) + (ln & 15)][(ln >> 4) * 8];

#pragma unroll
  for (int ch = 0; ch < 12; ++ch) {
    const int kl = ch * 32;
    const bool ph2 = (ch >= 4 && ch < 8);
    uint4 a0 = make_uint4(0, 0, 0, 0), a1 = make_uint4(0, 0, 0, 0);
    if (!ph2) {
      int acol = (ch < 4 ? kl : kl - 64) + aq * 8;
      if (valid) {
        a0 = *reinterpret_cast<const uint4*>(aptr + acol);
        a1 = *reinterpret_cast<const uint4*>(aptr + acol + 4);
      }
    } else {
      int acol = 128 + ((kl - 128) >> 1) + aq * 4;
      if (valid) a0 = *reinterpret_cast<const uint4*>(aptr + acol);
    }
    uint4 w0 = *reinterpret_cast<const uint4*>(wptr + kl);
    uint4 w1 = *reinterpret_cast<const uint4*>(wptr + kl + 4);
    uint4 w2 = *reinterpret_cast<const uint4*>(wptr + kl + 8);
    uint4 w3 = *reinterpret_cast<const uint4*>(wptr + kl + 12);

    __syncthreads();

    if (!ph2) {
      u32 va[8] = {a0.x, a0.y, a0.z, a0.w, a1.x, a1.y, a1.z, a1.w};
      short8 h, l;
#pragma unroll
      for (int j = 0; j < 8; ++j) { h[j] = (short)(va[j] & 0xffffu); l[j] = (short)(va[j] >> 16); }
      *reinterpret_cast<short8*>(&Ah[ar][aq * 8]) = h;
      *reinterpret_cast<short8*>(&Al[ar][aq * 8]) = l;
    } else {
      *reinterpret_cast<short8*>(&Ah[ar][aq * 8]) = *reinterpret_cast<const short8*>(&a0);
    }
    {
      u32 vw[16] = {w0.x, w0.y, w0.z, w0.w, w1.x, w1.y, w1.z, w1.w,
                    w2.x, w2.y, w2.z, w2.w, w3.x, w3.y, w3.z, w3.w};
      short8 h0, l0, h1, l1;
#pragma unroll
      for (int j = 0; j < 8; ++j) {
        h0[j] = (short)(vw[j] & 0xffffu);     l0[j] = (short)(vw[j] >> 16);
        h1[j] = (short)(vw[j + 8] & 0xffffu); l1[j] = (short)(vw[j + 8] >> 16);
      }
      *reinterpret_cast<short8*>(&Wh[wc][wk]) = h0;
      *reinterpret_cast<short8*>(&Wh[wc][wk + 8]) = h1;
      *reinterpret_cast<short8*>(&Wl[wc][wk]) = l0;
      *reinterpret_cast<short8*>(&Wl[wc][wk + 8]) = l1;
    }

    __syncthreads();

    short8 ah = *reinterpret_cast<const short8*>(afh);
    short8 al = *reinterpret_cast<const short8*>(afl);
#pragma unroll
    for (int nt = 0; nt < 8; ++nt) {
      short8 bh = *reinterpret_cast<const short8*>(&Wh[nt * 16 + (ln & 15)][(ln >> 4) * 8]);
      short8 bl = *reinterpret_cast<const short8*>(&Wl[nt * 16 + (ln & 15)][(ln >> 4) * 8]);
      acc[nt] = __builtin_amdgcn_mfma_f32_16x16x32_bf16(ah, bh, acc[nt], 0, 0, 0);
      if (!ph2) acc[nt] = __builtin_amdgcn_mfma_f32_16x16x32_bf16(al, bh, acc[nt], 0, 0, 0);
      acc[nt] = __builtin_amdgcn_mfma_f32_16x16x32_bf16(ah, bl, acc[nt], 0, 0, 0);
    }
  }

  // epilogue: write out + accumulate BN stats (sum, sumsq) per channel
  int rbase = node0 + (wv << 4) + ((ln >> 4) << 2);
  int colb = ln & 15;
#pragma unroll
  for (int nt = 0; nt < 8; ++nt) {
    int col = nt * 16 + colb;
    float bb = bv[col];
    float s = 0.f, q = 0.f;
#pragma unroll
    for (int r = 0; r < 4; ++r) {
      int n = rbase + r;
      if (n < N_NODES) {
        float v = acc[nt][r] + bb;
        out[(size_t)n * DH + col] = v;
        s += v; q += v * v;
      }
    }
    atomicAdd(&sstat[col], s);
    atomicAdd(&qstat[col], q);
  }
  __syncthreads();
  for (int i = tid; i < DH; i += 256) {
    atomicAdd(&stats[i], sstat[i]);
    atomicAdd(&stats[128 + i], qstat[i]);
  }
}

// BN + ELU -> h16 plane (bf16)
__global__ void k_bnapply(const float* __restrict__ x, const float* __restrict__ stats,
                          const float* __restrict__ g, const float* __restrict__ be,
                          u32* __restrict__ A) {
  int idx = blockIdx.x * 256 + threadIdx.x;
  if (idx >= N_NODES * DH) return;
  int n = idx >> 7, c = idx & 127;
  float mu = stats[c] * (1.0f / N_NODES);
  float var = stats[128 + c] * (1.0f / N_NODES) - mu * mu;
  float y = (x[idx] - mu) * rsqrtf(var + BN_EPS) * g[c] + be[c];
  y = y > 0.f ? y : expm1f(y);
  ((u16*)(A + (size_t)n * AS + 128))[c] = f2bf(y);
}

// ---------------- layer 2 (project-first, dout=2) ----------------
__global__ void k_l2_dense(const u32* __restrict__ A,
                           const float* __restrict__ Wm2, const float* __restrict__ bm2,
                           const float* __restrict__ Wr2, const float* __restrict__ br2,
                           float* __restrict__ val, float* __restrict__ pm) {
  int wave = threadIdx.x >> 6, lane = threadIdx.x & 63;
  int n = blockIdx.x * 4 + wave;
  if (n >= N_NODES) return;
  const u32* ar = A + (size_t)n * AS;
  const u16* h16 = (const u16*)(ar + 128);
  float h0 = bf2f(h16[lane]);
  float h1 = bf2f(h16[lane + 64]);
  float e0 = unpack_hl(ar[192 + lane]);
  float e1 = (lane < DE - 64) ? unpack_hl(ar[256 + lane]) : 0.f;

  float pm0 = h0 * Wm2[lane] + h1 * Wm2[lane + 64];
  float pm1 = h0 * Wm2[FM + lane] + h1 * Wm2[FM + lane + 64];
  float ve0 = e0 * Wm2[DIN + lane] + ((lane < DE - 64) ? e1 * Wm2[DIN + lane + 64] : 0.f);
  float ve1 = e0 * Wm2[FM + DIN + lane] + ((lane < DE - 64) ? e1 * Wm2[FM + DIN + lane + 64] : 0.f);
  float pr0 = h0 * Wr2[lane] + h1 * Wr2[lane + 64];
  float pr1 = h0 * Wr2[DH + lane] + h1 * Wr2[DH + lane + 64];

#pragma unroll
  for (int m = 32; m >= 1; m >>= 1) {
    pm0 += __shfl_xor(pm0, m, 64); pm1 += __shfl_xor(pm1, m, 64);
    ve0 += __shfl_xor(ve0, m, 64); ve1 += __shfl_xor(ve1, m, 64);
    pr0 += __shfl_xor(pr0, m, 64); pr1 += __shfl_xor(pr1, m, 64);
  }
  if (lane == 0) {
    val[n * 2 + 0] = 0.5f * (ve0 + bm2[0]) + pr0 + br2[0];
    val[n * 2 + 1] = 0.5f * (ve1 + bm2[1]) + pr1 + br2[1];
    pm[n * 2 + 0] = pm0;
    pm[n * 2 + 1] = pm1;
  }
}

__global__ void k_agg2(const int* __restrict__ row_ptr, const uint2* __restrict__ er_s,
                       const float* __restrict__ pm, float* __restrict__ val) {
  int n = blockIdx.x * 256 + threadIdx.x;
  if (n >= N_NODES) return;
  float a0 = 0.f, a1 = 0.f;
  int s = row_ptr[n], e = row_ptr[n + 1];
  for (int p = s; p < e; ++p) {
    int c = er_s[p].x & 0xffff;
    a0 += pm[c * 2]; a1 += pm[c * 2 + 1];
  }
  val[n * 2] += 0.5f * a0;
  val[n * 2 + 1] += 0.5f * a1;
}

__global__ void k_bnstats2(const float* __restrict__ val, float* __restrict__ s4) {
  float s0 = 0.f, q0 = 0.f, s1 = 0.f, q1 = 0.f;
  for (int n = blockIdx.x * 256 + threadIdx.x; n < N_NODES; n += gridDim.x * 256) {
    float v0 = val[n * 2], v1 = val[n * 2 + 1];
    s0 += v0; q0 += v0 * v0; s1 += v1; q1 += v1 * v1;
  }
  __shared__ float b[256][4];
  b[threadIdx.x][0] = s0; b[threadIdx.x][1] = q0;
  b[threadIdx.x][2] = s1; b[threadIdx.x][3] = q1;
  __syncthreads();
  for (int off = 128; off >= 1; off >>= 1) {
    if (threadIdx.x < off)
      for (int j = 0; j < 4; ++j) b[threadIdx.x][j] += b[threadIdx.x + off][j];
    __syncthreads();
  }
  if (threadIdx.x == 0)
    for (int j = 0; j < 4; ++j) atomicAdd(&s4[j], b[0][j]);
}

__global__ void k_final(const float* __restrict__ val, const float* __restrict__ s4,
                        const float* __restrict__ g2, const float* __restrict__ be2,
                        float* __restrict__ out) {
  int n = blockIdx.x * 256 + threadIdx.x;
  if (n >= N_NODES) return;
  float mu0 = s4[0] * (1.f / N_NODES), var0 = s4[1] * (1.f / N_NODES) - mu0 * mu0;
  float mu1 = s4[2] * (1.f / N_NODES), var1 = s4[3] * (1.f / N_NODES) - mu1 * mu1;
  float y0 = (val[n * 2] - mu0) * rsqrtf(var0 + BN_EPS) * g2[0] + be2[0];
  float y1 = (val[n * 2 + 1] - mu1) * rsqrtf(var1 + BN_EPS) * g2[1] + be2[1];
  float m = fmaxf(y0, y1);
  float lse = m + __logf(__expf(y0 - m) + __expf(y1 - m));
  out[n * 2] = y0 - lse;
  out[n * 2 + 1] = y1 - lse;
}

// ---------------- launch ----------------
extern "C" void kernel_launch(void* const* d_in, const int* in_sizes, int n_in,
                              void* d_out, int out_size, void* d_ws, size_t ws_size,
                              hipStream_t stream) {
  (void)in_sizes; (void)n_in; (void)out_size; (void)ws_size;
  const float* x        = (const float*)d_in[0];
  const int*   eidx     = (const int*)d_in[1];
  const int*   row      = eidx;
  const int*   col      = eidx + N_EDGES;
  const int*   attr     = (const int*)d_in[2];
  const int*   tim      = (const int*)d_in[3];
  const int*   dire     = (const int*)d_in[4];
  const float* emb_type = (const float*)d_in[5];
  const float* emb_dir  = (const float*)d_in[6];
  const float* w_t      = (const float*)d_in[7];
  const float* b_t      = (const float*)d_in[8];
  const float* Wm[3] = {(const float*)d_in[9],  (const float*)d_in[15], (const float*)d_in[21]};
  const float* bm[3] = {(const float*)d_in[10], (const float*)d_in[16], (const float*)d_in[22]};
  const float* Wr[3] = {(const float*)d_in[11], (const float*)d_in[17], (const float*)d_in[23]};
  const float* br[3] = {(const float*)d_in[12], (const float*)d_in[18], (const float*)d_in[24]};
  const float* g[3]  = {(const float*)d_in[13], (const float*)d_in[19], (const float*)d_in[25]};
  const float* be[3] = {(const float*)d_in[14], (const float*)d_in[20], (const float*)d_in[26]};
  float* out = (float*)d_out;

  // workspace layout (~97 MB)
  char* p = (char*)d_ws;
  u32* A     = (u32*)p;   p += sizeof(u32) * (size_t)N_NODES * AS;    // 64 MB
  float* gout = (float*)p; p += sizeof(float) * (size_t)N_NODES * DH; // 25.6 MB
  uint2* er_s = (uint2*)p; p += sizeof(uint2) * (size_t)N_EDGES;      // 6.4 MB
  u32* WT2[2];
  WT2[0] = (u32*)p; p += sizeof(u32) * DH * WKL;
  WT2[1] = (u32*)p; p += sizeof(u32) * DH * WKL;
  float* bv[2];
  bv[0] = (float*)p; p += sizeof(float) * DH;
  bv[1] = (float*)p; p += sizeof(float) * DH;
  float* val  = (float*)p;  p += sizeof(float) * (size_t)N_NODES * 2;
  float* pmb  = (float*)p;  p += sizeof(float) * (size_t)N_NODES * 2;
  float* stats = (float*)p; p += sizeof(float) * 520;
  int* counts  = (int*)p;   p += sizeof(int) * N_NODES;
  int* cursor  = (int*)p;   p += sizeof(int) * N_NODES;
  int* row_ptr = (int*)p;   p += sizeof(int) * (N_NODES + 1);
  int* incl    = (int*)p;   p += sizeof(int) * N_NODES;
  int* bsum    = (int*)p;   p += sizeof(int) * SCAN_NB;
  int* boff    = (int*)p;   p += sizeof(int) * SCAN_NB;

  const int EB = (N_EDGES + 255) / 256;      // 3125
  const int NB = (N_NODES + 255) / 256;      // 196
  const int AB = (N_NODES + 3) / 4;          // 12500
  const int GB = (N_NODES + 63) / 64;        // 782
  const int XB = (N_NODES * DH + 255) / 256; // 25000
  const int WB = (DH * WKL + 255) / 256;     // 192

  hipMemsetAsync(counts, 0, sizeof(int) * N_NODES, stream);
  hipMemsetAsync(stats, 0, sizeof(float) * 520, stream);

  // CSR
  k_count<<<EB, 256, 0, stream>>>(row, counts);
  k_scan_a<<<SCAN_NB, 256, 0, stream>>>(counts, incl, bsum);
  k_scan_b<<<1, 256, 0, stream>>>(bsum, boff, row_ptr);
  k_scan_c<<<SCAN_NB, 256, 0, stream>>>(incl, counts, boff, row_ptr, cursor);
  k_fill<<<EB, 256, 0, stream>>>(row, col, attr, dire, tim, cursor, er_s);

  // weight prep
  for (int l = 0; l < 2; ++l) {
    k_wprep<<<WB, 256, 0, stream>>>(Wm[l], Wr[l], WT2[l]);
    k_bias<<<1, 128, 0, stream>>>(bm[l], br[l], bv[l]);
  }

  // x -> h16 plane; edge features -> e region (+pad)
  k_conv_x<<<XB, 256, 0, stream>>>(x, A);
  k_aggE<<<N_NODES, 128, 0, stream>>>(row_ptr, er_s, emb_type, emb_dir, w_t, b_t, A);

  // layer 0
  k_aggH<<<AB, 256, 0, stream>>>(row_ptr, er_s, A);
  k_mfma<<<GB, 256, 0, stream>>>(A, WT2[0], bv[0], gout, stats);
  k_bnapply<<<XB, 256, 0, stream>>>(gout, stats, g[0], be[0], A);

  // layer 1
  k_aggH<<<AB, 256, 0, stream>>>(row_ptr, er_s, A);
  k_mfma<<<GB, 256, 0, stream>>>(A, WT2[1], bv[1], gout, stats + 256);
  k_bnapply<<<XB, 256, 0, stream>>>(gout, stats + 256, g[1], be[1], A);

  // layer 2
  k_l2_dense<<<AB, 256, 0, stream>>>(A, Wm[2], bm[2], Wr[2], br[2], val, pmb);
  k_agg2<<<NB, 256, 0, stream>>>(row_ptr, er_s, pmb, val);
  k_bnstats2<<<64, 256, 0, stream>>>(val, stats + 512);
  k_final<<<NB, 256, 0, stream>>>(val, stats + 512, g[2], be[2], out);
}